// Round 9
// baseline (338.669 us; speedup 1.0000x reference)
//
#include <hip/hip_runtime.h>
#include <math.h>

#define N_NODES   50000
#define F_IN      2048
#define E_ADJ     800000
#define NNZ_FEAT  1600000
#define HID       64
#define NCLS      40

// Fixed-capacity per-row slabs (degrees Poisson(32)/Poisson(16), max ~58/~35).
#define SLAB_F    80    // 640 B / row (multiple of 8)
#define SLAB_A    48    // 384 B / row (multiple of 8)

// One fill counter per 64B cache line.
#define FILL_STRIDE 16

// Radix-partition geometry. 256 rows/bucket -> pass-2 scatter window =
// 256*640B = 160KB (feat) / 96KB (adj): far below one XCD's 4MB L2, so slab
// lines fill completely before eviction (round-7 failure: 6.4MB bin > 4MB L2).
#define RPB       256
#define NBUCK     196                       // ceil(50000/256)
#define BCAP_F    9216                      // mean 8192, +11 sigma
#define BCAP_A    4800                      // mean 4096, +11 sigma
#define IPT       8
#define CHUNK_ITEMS (256 * IPT)             // 2048
#define FEAT_CHUNKS ((NNZ_FEAT + CHUNK_ITEMS - 1) / CHUNK_ITEMS)   // 782
#define ADJ_CHUNKS  ((E_ADJ  + CHUNK_ITEMS - 1) / CHUNK_ITEMS)     // 391

// WORKSPACE BUDGET: every passing round used <= ~90.4 MB; round 8 (container
// death) grew to ~112.5 MB by allocating barrF/barrA fresh. ws_size was never
// verified, so we alias instead: barrF -> hb, barrA -> xb (both dead until
// spmm_feat, which runs after bscatter). Total stays at round 7's footprint.

typedef unsigned short ushort_t;
typedef unsigned int   uint_t;
typedef _Float16 half8v __attribute__((ext_vector_type(8)));
typedef float    float4v __attribute__((ext_vector_type(4)));

// ---------------------------------------------------------------------------
// PASS 1: partition COO items into per-bucket append arrays.
// Single scan of the item stream (round 7 scanned it 8x). Per block: LDS
// bucket counts -> one global atomic per touched bucket -> LDS bucket-major
// staging -> coalesced contiguous writes. Entry: x = (col<<8)|rowInBucket,
// y = fp32 value bits.
// ---------------------------------------------------------------------------
__global__ void partition_kernel(const int* __restrict__ fi, const float* __restrict__ fv,
                                 const int* __restrict__ ai, const float* __restrict__ av,
                                 int* __restrict__ bfF, int2* __restrict__ barrF,
                                 int* __restrict__ bfA, int2* __restrict__ barrA) {
    __shared__ int  cnt[NBUCK + 1];
    __shared__ int  scan[NBUCK];
    __shared__ int  gbase[NBUCK];
    __shared__ int2 sItem[CHUNK_ITEMS];
    __shared__ int  sDst[CHUNK_ITEMS];

    int bid = blockIdx.x;
    bool isF = bid < FEAT_CHUNKS;
    const int* rows; const int* cols; const float* vals;
    int n, chunk, bcap; int* bfill; int2* barr;
    if (isF) { rows = fi; cols = fi + NNZ_FEAT; vals = fv; n = NNZ_FEAT;
               bfill = bfF; barr = barrF; bcap = BCAP_F; chunk = bid; }
    else     { rows = ai; cols = ai + E_ADJ;   vals = av; n = E_ADJ;
               bfill = bfA; barr = barrA; bcap = BCAP_A; chunk = bid - FEAT_CHUNKS; }

    int t = threadIdx.x;
    for (int i = t; i < NBUCK + 1; i += 256) cnt[i] = 0;
    __syncthreads();

    int ibase = chunk * CHUNK_ITEMS + t;
    int rr[IPT], cc[IPT], bk[IPT], sl[IPT]; float vv[IPT];
#pragma unroll
    for (int k = 0; k < IPT; ++k) {
        int i = ibase + k * 256;
        bk[k] = -1;
        if (i < n) {
            rr[k] = rows[i]; cc[k] = cols[i]; vv[k] = vals[i];
            bk[k] = rr[k] >> 8;                       // RPB = 256
            sl[k] = atomicAdd(&cnt[bk[k]], 1);
        }
    }
    __syncthreads();

    if (t == 0) {                                     // exclusive scan (196 adds)
        int s = 0;
        for (int b = 0; b < NBUCK; ++b) { scan[b] = s; s += cnt[b]; }
        cnt[NBUCK] = s;
    }
    __syncthreads();
    for (int b = t; b < NBUCK; b += 256)
        gbase[b] = cnt[b] ? atomicAdd(&bfill[b], cnt[b]) : 0;
    __syncthreads();

#pragma unroll
    for (int k = 0; k < IPT; ++k) {
        if (bk[k] >= 0) {
            int pos = scan[bk[k]] + sl[k];             // block-local bucket-major
            int gp  = gbase[bk[k]] + sl[k];            // position in bucket array
            int2 e; e.x = (cc[k] << 8) | (rr[k] & 255); e.y = __float_as_int(vv[k]);
            sItem[pos] = e;
            sDst[pos]  = (gp < bcap) ? (bk[k] * bcap + gp) : -1;
        }
    }
    __syncthreads();

    int total = cnt[NBUCK];
    for (int j = t; j < total; j += 256) {             // coalesced: runs are contiguous
        int d = sDst[j];
        if (d >= 0) barr[d] = sItem[j];
    }
}

// ---------------------------------------------------------------------------
// PASS 2: per-bucket scatter into row slabs. One block per bucket; all
// stores land in a 160KB/96KB window resident in the block's XCD L2, so each
// slab line is written back once. Slot order nondeterministic (as before).
// Slab entry: x = pre-scaled byte offset (col*stride), y = value bits.
// ---------------------------------------------------------------------------
__global__ void bscatter_kernel(const int* __restrict__ bfF, const int2* __restrict__ barrF,
                                const int* __restrict__ bfA, const int2* __restrict__ barrA,
                                int* __restrict__ featFill, int2* __restrict__ featSlab,
                                int* __restrict__ adjFill,  int2* __restrict__ adjSlab) {
    int b = blockIdx.x;
    bool isF = b < NBUCK;
    int bb; const int* bf; const int2* barr; int bcap, cap, scale;
    int* fill; int2* slab;
    if (isF) { bb = b;          bf = bfF; barr = barrF; bcap = BCAP_F;
               fill = featFill; slab = featSlab; cap = SLAB_F; scale = 384; }
    else     { bb = b - NBUCK;  bf = bfA; barr = barrA; bcap = BCAP_A;
               fill = adjFill;  slab = adjSlab;  cap = SLAB_A; scale = 128; }

    int n = min(bf[bb], bcap);
    int rbase = bb << 8;
    const int2* arr = barr + (size_t)bb * bcap;
    for (int i = threadIdx.x; i < n; i += 256) {
        int2 e = arr[i];
        int r = rbase + (e.x & 255);
        int c = e.x >> 8;
        int p = atomicAdd(&fill[(size_t)r * FILL_STRIDE], 1);
        if (p < cap) {
            int2 o; o.x = c * scale; o.y = e.y;
            slab[(size_t)r * cap + p] = o;
        }
    }
}

// ---------------------------------------------------------------------------
// Zero-pad each slab row from its fill count up to roundup8(max over the row
// PAIR {r, r^1}). Padded entries are {byteoff 0, value 0.0f} -> fma no-ops.
// ---------------------------------------------------------------------------
__global__ void slab_pad_kernel(const int* __restrict__ featFill, int2* __restrict__ featSlab,
                                const int* __restrict__ adjFill,  int2* __restrict__ adjSlab) {
    int i = blockIdx.x * blockDim.x + threadIdx.x;
    const int perSlab = N_NODES * 8;
    const int* fill; int2* slab; int cap; int idx;
    if (i < perSlab)              { fill = featFill; slab = featSlab; cap = SLAB_F; idx = i; }
    else if (i < 2 * perSlab)     { fill = adjFill;  slab = adjSlab;  cap = SLAB_A; idx = i - perSlab; }
    else return;
    int r  = idx >> 3;
    int k  = idx & 7;
    int rm = r ^ 1;
    int s  = min(fill[(size_t)r  * FILL_STRIDE], cap);
    int sm = min(fill[(size_t)rm * FILL_STRIDE], cap);
    int tgt = (max(s, sm) + 7) & ~7;   // <= cap since cap % 8 == 0
    int2 z; z.x = 0; z.y = 0;
    for (int slot = s + k; slot < tgt; slot += 8)
        slab[(size_t)r * cap + slot] = z;
}

// Fused weight prep: w1|w2|w3 -> fp16 wcat[2048][192], and
// fc_w [192x40] -> class-major fp16 fcwB[48][192] (cols 40..47 zero).
__global__ void prep_kernel(const float* __restrict__ w1, const float* __restrict__ w2,
                            const float* __restrict__ w3, _Float16* __restrict__ wcat,
                            const float* __restrict__ fc_w, _Float16* __restrict__ fcwB) {
    int i = blockIdx.x * blockDim.x + threadIdx.x;
    if (i < F_IN * HID) {
        int f = i >> 6, c = i & 63;
        wcat[(size_t)f * 192 + c]       = (_Float16)w1[i];
        wcat[(size_t)f * 192 + 64 + c]  = (_Float16)w2[i];
        wcat[(size_t)f * 192 + 128 + c] = (_Float16)w3[i];
    } else {
        int j = i - F_IN * HID;
        if (j < 48 * 192) {
            int c = j / 192, k = j - c * 192;
            fcwB[j] = (c < NCLS) ? (_Float16)fc_w[k * NCLS + c] : (_Float16)0.0f;
        }
    }
}

static __device__ inline float h_at(const void* base, uint_t byteoff) {
    return (float)*(const _Float16*)((const char*)base + byteoff);
}

// ---------------------------------------------------------------------------
// SpMM feat @ wcat + bias, relu. One block (3 waves) per ROW PAIR; thread t
// owns output col t of 192 for BOTH rows -> two independent gather streams.
// (Round-6 proven form.) Branch0 -> hb[:,0:64]; br 1,2 -> xb[N,128].
// ---------------------------------------------------------------------------
__global__ void spmm_feat_kernel(const int* __restrict__ fill, const int2* __restrict__ slab,
                                 const _Float16* __restrict__ wcat,
                                 const float* __restrict__ b1, const float* __restrict__ b2,
                                 const float* __restrict__ b3,
                                 _Float16* __restrict__ hb, _Float16* __restrict__ xb) {
    int bp = blockIdx.x;
    int r0 = 2 * bp, r1 = 2 * bp + 1;
    int t  = threadIdx.x;       // 0..191
    int br = t >> 6;
    int c  = t & 63;
    const float* b = (br == 0) ? b1 : (br == 1) ? b2 : b3;
    float bias = b[c];
    float acc0 = bias, acc1 = bias;
    uint_t t2 = 2u * (uint_t)t;
    const int2* s0v = slab + (size_t)r0 * SLAB_F;
    const int2* s1v = slab + (size_t)r1 * SLAB_F;
    int f0 = min(fill[(size_t)r0 * FILL_STRIDE], SLAB_F);
    int f1 = min(fill[(size_t)r1 * FILL_STRIDE], SLAB_F);
    int e  = (max(f0, f1) + 7) & ~7;
    for (int j = 0; j < e; j += 8) {
        int4 p0 = *(const int4*)&s0v[j];
        int4 p1 = *(const int4*)&s0v[j + 2];
        int4 p2 = *(const int4*)&s0v[j + 4];
        int4 p3 = *(const int4*)&s0v[j + 6];
        int4 q0 = *(const int4*)&s1v[j];
        int4 q1 = *(const int4*)&s1v[j + 2];
        int4 q2 = *(const int4*)&s1v[j + 4];
        int4 q3 = *(const int4*)&s1v[j + 6];
        float f0v = h_at(wcat, (uint_t)p0.x + t2);
        float f1v = h_at(wcat, (uint_t)p0.z + t2);
        float f2v = h_at(wcat, (uint_t)p1.x + t2);
        float f3v = h_at(wcat, (uint_t)p1.z + t2);
        float f4v = h_at(wcat, (uint_t)p2.x + t2);
        float f5v = h_at(wcat, (uint_t)p2.z + t2);
        float f6v = h_at(wcat, (uint_t)p3.x + t2);
        float f7v = h_at(wcat, (uint_t)p3.z + t2);
        float g0v = h_at(wcat, (uint_t)q0.x + t2);
        float g1v = h_at(wcat, (uint_t)q0.z + t2);
        float g2v = h_at(wcat, (uint_t)q1.x + t2);
        float g3v = h_at(wcat, (uint_t)q1.z + t2);
        float g4v = h_at(wcat, (uint_t)q2.x + t2);
        float g5v = h_at(wcat, (uint_t)q2.z + t2);
        float g6v = h_at(wcat, (uint_t)q3.x + t2);
        float g7v = h_at(wcat, (uint_t)q3.z + t2);
        acc0 = fmaf(__int_as_float(p0.y), f0v, acc0);
        acc0 = fmaf(__int_as_float(p0.w), f1v, acc0);
        acc0 = fmaf(__int_as_float(p1.y), f2v, acc0);
        acc0 = fmaf(__int_as_float(p1.w), f3v, acc0);
        acc0 = fmaf(__int_as_float(p2.y), f4v, acc0);
        acc0 = fmaf(__int_as_float(p2.w), f5v, acc0);
        acc0 = fmaf(__int_as_float(p3.y), f6v, acc0);
        acc0 = fmaf(__int_as_float(p3.w), f7v, acc0);
        acc1 = fmaf(__int_as_float(q0.y), g0v, acc1);
        acc1 = fmaf(__int_as_float(q0.w), g1v, acc1);
        acc1 = fmaf(__int_as_float(q1.y), g2v, acc1);
        acc1 = fmaf(__int_as_float(q1.w), g3v, acc1);
        acc1 = fmaf(__int_as_float(q2.y), g4v, acc1);
        acc1 = fmaf(__int_as_float(q2.w), g5v, acc1);
        acc1 = fmaf(__int_as_float(q3.y), g6v, acc1);
        acc1 = fmaf(__int_as_float(q3.w), g7v, acc1);
    }
    acc0 = fmaxf(acc0, 0.0f);
    acc1 = fmaxf(acc1, 0.0f);
    if (br == 0) {
        hb[(size_t)r0 * 192 + c] = (_Float16)acc0;
        hb[(size_t)r1 * 192 + c] = (_Float16)acc1;
    } else {
        xb[(size_t)r0 * 128 + (size_t)(br - 1) * 64 + c] = (_Float16)acc0;
        xb[(size_t)r1 * 128 + (size_t)(br - 1) * 64 + c] = (_Float16)acc1;
    }
}

// hop1: y = A @ xb. Slab e.x = col*128; xb byte stride 256 -> off = (e.x<<1)+t2.
// One block (2 waves) per ROW PAIR. branch1 -> hb[:,64:128]; branch2 -> tmp.
__global__ void hop1_kernel(const int* __restrict__ fill, const int2* __restrict__ slab,
                            const _Float16* __restrict__ xb,
                            _Float16* __restrict__ hb, _Float16* __restrict__ tmp) {
    int bp = blockIdx.x;
    int r0 = 2 * bp, r1 = 2 * bp + 1;
    int t = threadIdx.x;        // 0..127
    float acc0 = 0.0f, acc1 = 0.0f;
    uint_t t2 = 2u * (uint_t)t;
    const int2* s0v = slab + (size_t)r0 * SLAB_A;
    const int2* s1v = slab + (size_t)r1 * SLAB_A;
    int f0 = min(fill[(size_t)r0 * FILL_STRIDE], SLAB_A);
    int f1 = min(fill[(size_t)r1 * FILL_STRIDE], SLAB_A);
    int e  = (max(f0, f1) + 7) & ~7;
    for (int j = 0; j < e; j += 8) {
        int4 p0 = *(const int4*)&s0v[j];
        int4 p1 = *(const int4*)&s0v[j + 2];
        int4 p2 = *(const int4*)&s0v[j + 4];
        int4 p3 = *(const int4*)&s0v[j + 6];
        int4 q0 = *(const int4*)&s1v[j];
        int4 q1 = *(const int4*)&s1v[j + 2];
        int4 q2 = *(const int4*)&s1v[j + 4];
        int4 q3 = *(const int4*)&s1v[j + 6];
        float f0v = h_at(xb, ((uint_t)p0.x << 1) + t2);
        float f1v = h_at(xb, ((uint_t)p0.z << 1) + t2);
        float f2v = h_at(xb, ((uint_t)p1.x << 1) + t2);
        float f3v = h_at(xb, ((uint_t)p1.z << 1) + t2);
        float f4v = h_at(xb, ((uint_t)p2.x << 1) + t2);
        float f5v = h_at(xb, ((uint_t)p2.z << 1) + t2);
        float f6v = h_at(xb, ((uint_t)p3.x << 1) + t2);
        float f7v = h_at(xb, ((uint_t)p3.z << 1) + t2);
        float g0v = h_at(xb, ((uint_t)q0.x << 1) + t2);
        float g1v = h_at(xb, ((uint_t)q0.z << 1) + t2);
        float g2v = h_at(xb, ((uint_t)q1.x << 1) + t2);
        float g3v = h_at(xb, ((uint_t)q1.z << 1) + t2);
        float g4v = h_at(xb, ((uint_t)q2.x << 1) + t2);
        float g5v = h_at(xb, ((uint_t)q2.z << 1) + t2);
        float g6v = h_at(xb, ((uint_t)q3.x << 1) + t2);
        float g7v = h_at(xb, ((uint_t)q3.z << 1) + t2);
        acc0 = fmaf(__int_as_float(p0.y), f0v, acc0);
        acc0 = fmaf(__int_as_float(p0.w), f1v, acc0);
        acc0 = fmaf(__int_as_float(p1.y), f2v, acc0);
        acc0 = fmaf(__int_as_float(p1.w), f3v, acc0);
        acc0 = fmaf(__int_as_float(p2.y), f4v, acc0);
        acc0 = fmaf(__int_as_float(p2.w), f5v, acc0);
        acc0 = fmaf(__int_as_float(p3.y), f6v, acc0);
        acc0 = fmaf(__int_as_float(p3.w), f7v, acc0);
        acc1 = fmaf(__int_as_float(q0.y), g0v, acc1);
        acc1 = fmaf(__int_as_float(q0.w), g1v, acc1);
        acc1 = fmaf(__int_as_float(q1.y), g2v, acc1);
        acc1 = fmaf(__int_as_float(q1.w), g3v, acc1);
        acc1 = fmaf(__int_as_float(q2.y), g4v, acc1);
        acc1 = fmaf(__int_as_float(q2.w), g5v, acc1);
        acc1 = fmaf(__int_as_float(q3.y), g6v, acc1);
        acc1 = fmaf(__int_as_float(q3.w), g7v, acc1);
    }
    if (t < 64) {
        hb[(size_t)r0 * 192 + 64 + t] = (_Float16)acc0;
        hb[(size_t)r1 * 192 + 64 + t] = (_Float16)acc1;
    } else {
        tmp[(size_t)r0 * 64 + (t - 64)] = (_Float16)acc0;
        tmp[(size_t)r1 * 64 + (t - 64)] = (_Float16)acc1;
    }
}

// hop2: branch2 second hop -> hb[:,128:192]. Slab e.x = col*128 = tmp byte off.
__global__ void hop2_kernel(const int* __restrict__ fill, const int2* __restrict__ slab,
                            const _Float16* __restrict__ tmp, _Float16* __restrict__ hb) {
    int bp = blockIdx.x;
    int r0 = 2 * bp, r1 = 2 * bp + 1;
    int t = threadIdx.x;        // 0..63
    float acc0 = 0.0f, acc1 = 0.0f;
    uint_t t2 = 2u * (uint_t)t;
    const int2* s0v = slab + (size_t)r0 * SLAB_A;
    const int2* s1v = slab + (size_t)r1 * SLAB_A;
    int f0 = min(fill[(size_t)r0 * FILL_STRIDE], SLAB_A);
    int f1 = min(fill[(size_t)r1 * FILL_STRIDE], SLAB_A);
    int e  = (max(f0, f1) + 7) & ~7;
    for (int j = 0; j < e; j += 8) {
        int4 p0 = *(const int4*)&s0v[j];
        int4 p1 = *(const int4*)&s0v[j + 2];
        int4 p2 = *(const int4*)&s0v[j + 4];
        int4 p3 = *(const int4*)&s0v[j + 6];
        int4 q0 = *(const int4*)&s1v[j];
        int4 q1 = *(const int4*)&s1v[j + 2];
        int4 q2 = *(const int4*)&s1v[j + 4];
        int4 q3 = *(const int4*)&s1v[j + 6];
        float f0v = h_at(tmp, (uint_t)p0.x + t2);
        float f1v = h_at(tmp, (uint_t)p0.z + t2);
        float f2v = h_at(tmp, (uint_t)p1.x + t2);
        float f3v = h_at(tmp, (uint_t)p1.z + t2);
        float f4v = h_at(tmp, (uint_t)p2.x + t2);
        float f5v = h_at(tmp, (uint_t)p2.z + t2);
        float f6v = h_at(tmp, (uint_t)p3.x + t2);
        float f7v = h_at(tmp, (uint_t)p3.z + t2);
        float g0v = h_at(tmp, (uint_t)q0.x + t2);
        float g1v = h_at(tmp, (uint_t)q0.z + t2);
        float g2v = h_at(tmp, (uint_t)q1.x + t2);
        float g3v = h_at(tmp, (uint_t)q1.z + t2);
        float g4v = h_at(tmp, (uint_t)q2.x + t2);
        float g5v = h_at(tmp, (uint_t)q2.z + t2);
        float g6v = h_at(tmp, (uint_t)q3.x + t2);
        float g7v = h_at(tmp, (uint_t)q3.z + t2);
        acc0 = fmaf(__int_as_float(p0.y), f0v, acc0);
        acc0 = fmaf(__int_as_float(p0.w), f1v, acc0);
        acc0 = fmaf(__int_as_float(p1.y), f2v, acc0);
        acc0 = fmaf(__int_as_float(p1.w), f3v, acc0);
        acc0 = fmaf(__int_as_float(p2.y), f4v, acc0);
        acc0 = fmaf(__int_as_float(p2.w), f5v, acc0);
        acc0 = fmaf(__int_as_float(p3.y), f6v, acc0);
        acc0 = fmaf(__int_as_float(p3.w), f7v, acc0);
        acc1 = fmaf(__int_as_float(q0.y), g0v, acc1);
        acc1 = fmaf(__int_as_float(q0.w), g1v, acc1);
        acc1 = fmaf(__int_as_float(q1.y), g2v, acc1);
        acc1 = fmaf(__int_as_float(q1.w), g3v, acc1);
        acc1 = fmaf(__int_as_float(q2.y), g4v, acc1);
        acc1 = fmaf(__int_as_float(q2.w), g5v, acc1);
        acc1 = fmaf(__int_as_float(q3.y), g6v, acc1);
        acc1 = fmaf(__int_as_float(q3.w), g7v, acc1);
    }
    hb[(size_t)r0 * 192 + 128 + t] = (_Float16)acc0;
    hb[(size_t)r1 * 192 + 128 + t] = (_Float16)acc1;
}

// ---------------------------------------------------------------------------
// FC + log_softmax via MFMA (f16). Block = 3 waves; wave nt owns 16 cols;
// 16 rows per block; K=192 = 6 x mfma_f32_16x16x32_f16.
// ---------------------------------------------------------------------------
__global__ void fc_mfma_kernel(const _Float16* __restrict__ hb,
                               const _Float16* __restrict__ fcwB,
                               const float* __restrict__ fc_b,
                               float* __restrict__ out) {
    int wave = threadIdx.x >> 6;      // 0..2 = N-tile
    int lane = threadIdx.x & 63;
    int m16  = lane & 15;
    int quad = lane >> 4;
    size_t rowbase = (size_t)blockIdx.x * 16;

    float4v acc = {0.f, 0.f, 0.f, 0.f};
    const _Float16* arow = hb   + (rowbase + m16) * 192 + quad * 8;
    const _Float16* brow = fcwB + (size_t)(wave * 16 + m16) * 192 + quad * 8;
#pragma unroll
    for (int s = 0; s < 6; ++s) {
        half8v a = *(const half8v*)(arow + s * 32);
        half8v b = *(const half8v*)(brow + s * 32);
        acc = __builtin_amdgcn_mfma_f32_16x16x32_f16(a, b, acc, 0, 0, 0);
    }

    __shared__ float lds[16][49];     // 48 cols + pad
    __shared__ float s_lse[16];
    int col = wave * 16 + m16;
    float bias = (col < NCLS) ? fc_b[col] : 0.0f;
#pragma unroll
    for (int i = 0; i < 4; ++i) {
        lds[quad * 4 + i][col] = acc[i] + bias;
    }
    __syncthreads();
    if (threadIdx.x < 16) {
        int row = threadIdx.x;
        float m = -INFINITY;
        for (int c = 0; c < NCLS; ++c) m = fmaxf(m, lds[row][c]);
        float s = 0.0f;
        for (int c = 0; c < NCLS; ++c) s += expf(lds[row][c] - m);
        s_lse[row] = m + logf(s);
    }
    __syncthreads();
    for (int idx = threadIdx.x; idx < 16 * NCLS; idx += 192) {
        int row = idx / NCLS, c = idx - row * NCLS;
        out[(rowbase + row) * NCLS + c] = lds[row][c] - s_lse[row];
    }
}

// ---------------------------------------------------------------------------

extern "C" void kernel_launch(void* const* d_in, const int* in_sizes, int n_in,
                              void* d_out, int out_size, void* d_ws, size_t ws_size,
                              hipStream_t stream) {
    const int*   adj_idx  = (const int*)  d_in[0];
    const float* adj_val  = (const float*)d_in[1];
    const int*   feat_idx = (const int*)  d_in[2];
    const float* feat_val = (const float*)d_in[3];
    const float* w1 = (const float*)d_in[4];
    const float* b1 = (const float*)d_in[5];
    const float* w2 = (const float*)d_in[6];
    const float* b2 = (const float*)d_in[7];
    const float* w3 = (const float*)d_in[8];
    const float* b3 = (const float*)d_in[9];
    const float* fc_w = (const float*)d_in[10];
    const float* fc_b = (const float*)d_in[11];
    float* out = (float*)d_out;

    char* ws = (char*)d_ws;
    size_t off = 0;
    auto take = [&](size_t bytes) -> char* {
        char* p = ws + off;
        off = (off + bytes + 255) & ~(size_t)255;
        return p;
    };
    // fills region: [featFill | adjFill | bfF(256) | bfA(256)] -- one memset.
    int*  fills    = (int*)take(((size_t)2 * N_NODES * FILL_STRIDE + 512) * sizeof(int));
    int*  featFill = fills;
    int*  adjFill  = fills + (size_t)N_NODES * FILL_STRIDE;
    int*  bfF      = fills + (size_t)2 * N_NODES * FILL_STRIDE;
    int*  bfA      = bfF + 256;
    int2* featSlab = (int2*)take((size_t)N_NODES * SLAB_F * sizeof(int2));        // 32 MB
    int2* adjSlab  = (int2*)take((size_t)N_NODES * SLAB_A * sizeof(int2));        // 19.2 MB
    _Float16* wcat = (_Float16*)take((size_t)F_IN * 192 * sizeof(_Float16));      // 0.79 MB
    _Float16* fcwB = (_Float16*)take((size_t)48 * 192 * sizeof(_Float16));        // 18 KB
    _Float16* xb   = (_Float16*)take((size_t)N_NODES * 128 * sizeof(_Float16));   // 12.8 MB
    _Float16* hb   = (_Float16*)take((size_t)N_NODES * 192 * sizeof(_Float16));   // 19.2 MB
    // Aliases (no new workspace -- total stays at the proven ~90.4 MB):
    //   barrF (14.5 MB) -> hb (19.2 MB): dead once bscatter completes.
    //   barrA ( 7.5 MB) -> xb (12.8 MB): dead once bscatter completes.
    //   tmp   ( 6.4 MB) -> featSlab (32 MB): featSlab dead after spmm_feat.
    int2* barrF = (int2*)hb;
    int2* barrA = (int2*)xb;
    _Float16* tmp = (_Float16*)featSlab;

    hipMemsetAsync(fills, 0, ((size_t)2 * N_NODES * FILL_STRIDE + 512) * sizeof(int), stream);

    prep_kernel<<<(F_IN * HID + 48 * 192 + 255) / 256, 256, 0, stream>>>(
        w1, w2, w3, wcat, fc_w, fcwB);

    partition_kernel<<<FEAT_CHUNKS + ADJ_CHUNKS, 256, 0, stream>>>(
        feat_idx, feat_val, adj_idx, adj_val, bfF, barrF, bfA, barrA);

    bscatter_kernel<<<2 * NBUCK, 256, 0, stream>>>(
        bfF, barrF, bfA, barrA, featFill, featSlab, adjFill, adjSlab);

    slab_pad_kernel<<<(2 * N_NODES * 8 + 255) / 256, 256, 0, stream>>>(
        featFill, featSlab, adjFill, adjSlab);

    spmm_feat_kernel<<<N_NODES / 2, 192, 0, stream>>>(featFill, featSlab, wcat,
                                                      b1, b2, b3, hb, xb);
    hop1_kernel<<<N_NODES / 2, 128, 0, stream>>>(adjFill, adjSlab, xb, hb, tmp);
    hop2_kernel<<<N_NODES / 2, 64, 0, stream>>>(adjFill, adjSlab, tmp, hb);
    fc_mfma_kernel<<<N_NODES / 16, 192, 0, stream>>>(hb, fcwB, fc_b, out);
}

// Round 10
// 258.813 us; speedup vs baseline: 1.3085x; 1.3085x over previous
//
#include <hip/hip_runtime.h>
#include <math.h>

#define N_NODES   50000
#define F_IN      2048
#define E_ADJ     800000
#define NNZ_FEAT  1600000
#define HID       64
#define NCLS      40

// Fixed-capacity per-row slabs (degrees Poisson(32)/Poisson(16), max ~58/~35).
#define SLAB_F    80    // 640 B / row (multiple of 8)
#define SLAB_A    48    // 384 B / row (multiple of 8)

// One fill counter per 64B cache line.
#define FILL_STRIDE 16

// Radix-partition geometry (pass 1, unchanged from round 9 -- proven).
#define RPB       256
#define NBUCK     196                       // ceil(50000/256)
#define BCAP_F    9216                      // mean 8192, +11 sigma
#define BCAP_A    4800                      // mean 4096, +11 sigma
#define IPT       8
#define CHUNK_ITEMS (256 * IPT)             // 2048
#define FEAT_CHUNKS ((NNZ_FEAT + CHUNK_ITEMS - 1) / CHUNK_ITEMS)   // 782
#define ADJ_CHUNKS  ((E_ADJ  + CHUNK_ITEMS - 1) / CHUNK_ITEMS)     // 391

// bscatter: one block per 64-row QUARTER bucket. LDS staging = 64*80*8B =
// 40KB (feat) -> atomic-free placement + fully coalesced int4 copy-out.
#define QROWS     64
#define QPB       4                          // quarters per bucket

// WORKSPACE: stays at the proven ~90.4 MB. barrF->hb, barrA->xb (dead before
// spmm_feat writes them); tmp->featSlab (dead after spmm_feat).

typedef unsigned short ushort_t;
typedef unsigned int   uint_t;
typedef _Float16 half8v __attribute__((ext_vector_type(8)));
typedef float    float4v __attribute__((ext_vector_type(4)));

// ---------------------------------------------------------------------------
// PASS 1: partition COO items into per-bucket append arrays (round-9 form).
// Entry: x = (col<<8)|rowInBucket, y = fp32 value bits.
// ---------------------------------------------------------------------------
__global__ void partition_kernel(const int* __restrict__ fi, const float* __restrict__ fv,
                                 const int* __restrict__ ai, const float* __restrict__ av,
                                 int* __restrict__ bfF, int2* __restrict__ barrF,
                                 int* __restrict__ bfA, int2* __restrict__ barrA) {
    __shared__ int  cnt[NBUCK + 1];
    __shared__ int  scan[NBUCK];
    __shared__ int  gbase[NBUCK];
    __shared__ int2 sItem[CHUNK_ITEMS];
    __shared__ int  sDst[CHUNK_ITEMS];

    int bid = blockIdx.x;
    bool isF = bid < FEAT_CHUNKS;
    const int* rows; const int* cols; const float* vals;
    int n, chunk, bcap; int* bfill; int2* barr;
    if (isF) { rows = fi; cols = fi + NNZ_FEAT; vals = fv; n = NNZ_FEAT;
               bfill = bfF; barr = barrF; bcap = BCAP_F; chunk = bid; }
    else     { rows = ai; cols = ai + E_ADJ;   vals = av; n = E_ADJ;
               bfill = bfA; barr = barrA; bcap = BCAP_A; chunk = bid - FEAT_CHUNKS; }

    int t = threadIdx.x;
    for (int i = t; i < NBUCK + 1; i += 256) cnt[i] = 0;
    __syncthreads();

    int ibase = chunk * CHUNK_ITEMS + t;
    int rr[IPT], cc[IPT], bk[IPT], sl[IPT]; float vv[IPT];
#pragma unroll
    for (int k = 0; k < IPT; ++k) {
        int i = ibase + k * 256;
        bk[k] = -1;
        if (i < n) {
            rr[k] = rows[i]; cc[k] = cols[i]; vv[k] = vals[i];
            bk[k] = rr[k] >> 8;                       // RPB = 256
            sl[k] = atomicAdd(&cnt[bk[k]], 1);
        }
    }
    __syncthreads();

    if (t == 0) {                                     // exclusive scan (196 adds)
        int s = 0;
        for (int b = 0; b < NBUCK; ++b) { scan[b] = s; s += cnt[b]; }
        cnt[NBUCK] = s;
    }
    __syncthreads();
    for (int b = t; b < NBUCK; b += 256)
        gbase[b] = cnt[b] ? atomicAdd(&bfill[b], cnt[b]) : 0;
    __syncthreads();

#pragma unroll
    for (int k = 0; k < IPT; ++k) {
        if (bk[k] >= 0) {
            int pos = scan[bk[k]] + sl[k];             // block-local bucket-major
            int gp  = gbase[bk[k]] + sl[k];            // position in bucket array
            int2 e; e.x = (cc[k] << 8) | (rr[k] & 255); e.y = __float_as_int(vv[k]);
            sItem[pos] = e;
            sDst[pos]  = (gp < bcap) ? (bk[k] * bcap + gp) : -1;
        }
    }
    __syncthreads();

    int total = cnt[NBUCK];
    for (int j = t; j < total; j += 256) {             // coalesced: runs are contiguous
        int d = sDst[j];
        if (d >= 0) barr[d] = sItem[j];
    }
}

// ---------------------------------------------------------------------------
// PASS 2: atomic-free quarter-bucket scatter. One block per 64 rows.
// Zero LDS staging (doubles as slab zero-padding) -> scan bucket items,
// LDS-atomic per-row offsets, place into staging -> plain-store fills ->
// coalesced int4 copy staging -> slab. No global atomics; replaces the
// round-9 bscatter (127us @ 14% occupancy, per-item global atomics) and the
// separate slab_pad kernel.
// ---------------------------------------------------------------------------
__global__ void bscatter_kernel(const int* __restrict__ bfF, const int2* __restrict__ barrF,
                                const int* __restrict__ bfA, const int2* __restrict__ barrA,
                                int* __restrict__ featFill, int2* __restrict__ featSlab,
                                int* __restrict__ adjFill,  int2* __restrict__ adjSlab) {
    __shared__ int2 stage[QROWS * SLAB_F];     // 40 KB (feat); adj uses prefix
    __shared__ int  off[QROWS];

    int b = blockIdx.x;
    bool isF = b < NBUCK * QPB;
    int bb, q; const int* bf; const int2* barr; int bcap, cap, scale;
    int* fill; int2* slab;
    if (isF) { bb = b >> 2; q = b & 3; bf = bfF; barr = barrF; bcap = BCAP_F;
               fill = featFill; slab = featSlab; cap = SLAB_F; scale = 384; }
    else     { b -= NBUCK * QPB; bb = b >> 2; q = b & 3;
               bf = bfA; barr = barrA; bcap = BCAP_A;
               fill = adjFill;  slab = adjSlab;  cap = SLAB_A; scale = 128; }

    int rbase = bb * RPB + q * QROWS;
    int nrows = min(QROWS, N_NODES - rbase);
    if (nrows <= 0) return;

    int t = threadIdx.x;
    int nstage = QROWS * cap;                  // 5120 (feat) / 3072 (adj) int2
    int4* s4 = (int4*)stage;
    for (int i = t; i < nstage / 2; i += 256) { int4 z = {0,0,0,0}; s4[i] = z; }
    if (t < QROWS) off[t] = 0;
    __syncthreads();

    int n = min(bf[bb], bcap);
    int qlo = q * QROWS;
    const int2* arr = barr + (size_t)bb * bcap;
    for (int i = t; i < n; i += 256) {
        int2 e = arr[i];
        int lr = (e.x & 255) - qlo;
        if ((unsigned)lr < (unsigned)QROWS) {
            int p = atomicAdd(&off[lr], 1);    // LDS atomic
            if (p < cap) {
                int2 o; o.x = (e.x >> 8) * scale; o.y = e.y;
                stage[lr * cap + p] = o;
            }
        }
    }
    __syncthreads();

    if (t < nrows) fill[(size_t)(rbase + t) * FILL_STRIDE] = off[t];
    int4* d4 = (int4*)(slab + (size_t)rbase * cap);
    int ncopy = nrows * cap / 2;               // int4 count
    for (int i = t; i < ncopy; i += 256) d4[i] = s4[i];
}

// Fused weight prep: w1|w2|w3 -> fp16 wcat[2048][192], and
// fc_w [192x40] -> class-major fp16 fcwB[48][192] (cols 40..47 zero).
__global__ void prep_kernel(const float* __restrict__ w1, const float* __restrict__ w2,
                            const float* __restrict__ w3, _Float16* __restrict__ wcat,
                            const float* __restrict__ fc_w, _Float16* __restrict__ fcwB) {
    int i = blockIdx.x * blockDim.x + threadIdx.x;
    if (i < F_IN * HID) {
        int f = i >> 6, c = i & 63;
        wcat[(size_t)f * 192 + c]       = (_Float16)w1[i];
        wcat[(size_t)f * 192 + 64 + c]  = (_Float16)w2[i];
        wcat[(size_t)f * 192 + 128 + c] = (_Float16)w3[i];
    } else {
        int j = i - F_IN * HID;
        if (j < 48 * 192) {
            int c = j / 192, k = j - c * 192;
            fcwB[j] = (c < NCLS) ? (_Float16)fc_w[k * NCLS + c] : (_Float16)0.0f;
        }
    }
}

static __device__ inline float h_at(const void* base, uint_t byteoff) {
    return (float)*(const _Float16*)((const char*)base + byteoff);
}

// ---------------------------------------------------------------------------
// SpMM feat @ wcat + bias, relu. One block (3 waves) per ROW PAIR; thread t
// owns output col t of 192 for BOTH rows -> two independent gather streams.
// (Round-6 proven form.) Branch0 -> hb[:,0:64]; br 1,2 -> xb[N,128].
// ---------------------------------------------------------------------------
__global__ void spmm_feat_kernel(const int* __restrict__ fill, const int2* __restrict__ slab,
                                 const _Float16* __restrict__ wcat,
                                 const float* __restrict__ b1, const float* __restrict__ b2,
                                 const float* __restrict__ b3,
                                 _Float16* __restrict__ hb, _Float16* __restrict__ xb) {
    int bp = blockIdx.x;
    int r0 = 2 * bp, r1 = 2 * bp + 1;
    int t  = threadIdx.x;       // 0..191
    int br = t >> 6;
    int c  = t & 63;
    const float* b = (br == 0) ? b1 : (br == 1) ? b2 : b3;
    float bias = b[c];
    float acc0 = bias, acc1 = bias;
    uint_t t2 = 2u * (uint_t)t;
    const int2* s0v = slab + (size_t)r0 * SLAB_F;
    const int2* s1v = slab + (size_t)r1 * SLAB_F;
    int f0 = min(fill[(size_t)r0 * FILL_STRIDE], SLAB_F);
    int f1 = min(fill[(size_t)r1 * FILL_STRIDE], SLAB_F);
    int e  = (max(f0, f1) + 7) & ~7;
    for (int j = 0; j < e; j += 8) {
        int4 p0 = *(const int4*)&s0v[j];
        int4 p1 = *(const int4*)&s0v[j + 2];
        int4 p2 = *(const int4*)&s0v[j + 4];
        int4 p3 = *(const int4*)&s0v[j + 6];
        int4 q0 = *(const int4*)&s1v[j];
        int4 q1 = *(const int4*)&s1v[j + 2];
        int4 q2 = *(const int4*)&s1v[j + 4];
        int4 q3 = *(const int4*)&s1v[j + 6];
        float f0v = h_at(wcat, (uint_t)p0.x + t2);
        float f1v = h_at(wcat, (uint_t)p0.z + t2);
        float f2v = h_at(wcat, (uint_t)p1.x + t2);
        float f3v = h_at(wcat, (uint_t)p1.z + t2);
        float f4v = h_at(wcat, (uint_t)p2.x + t2);
        float f5v = h_at(wcat, (uint_t)p2.z + t2);
        float f6v = h_at(wcat, (uint_t)p3.x + t2);
        float f7v = h_at(wcat, (uint_t)p3.z + t2);
        float g0v = h_at(wcat, (uint_t)q0.x + t2);
        float g1v = h_at(wcat, (uint_t)q0.z + t2);
        float g2v = h_at(wcat, (uint_t)q1.x + t2);
        float g3v = h_at(wcat, (uint_t)q1.z + t2);
        float g4v = h_at(wcat, (uint_t)q2.x + t2);
        float g5v = h_at(wcat, (uint_t)q2.z + t2);
        float g6v = h_at(wcat, (uint_t)q3.x + t2);
        float g7v = h_at(wcat, (uint_t)q3.z + t2);
        acc0 = fmaf(__int_as_float(p0.y), f0v, acc0);
        acc0 = fmaf(__int_as_float(p0.w), f1v, acc0);
        acc0 = fmaf(__int_as_float(p1.y), f2v, acc0);
        acc0 = fmaf(__int_as_float(p1.w), f3v, acc0);
        acc0 = fmaf(__int_as_float(p2.y), f4v, acc0);
        acc0 = fmaf(__int_as_float(p2.w), f5v, acc0);
        acc0 = fmaf(__int_as_float(p3.y), f6v, acc0);
        acc0 = fmaf(__int_as_float(p3.w), f7v, acc0);
        acc1 = fmaf(__int_as_float(q0.y), g0v, acc1);
        acc1 = fmaf(__int_as_float(q0.w), g1v, acc1);
        acc1 = fmaf(__int_as_float(q1.y), g2v, acc1);
        acc1 = fmaf(__int_as_float(q1.w), g3v, acc1);
        acc1 = fmaf(__int_as_float(q2.y), g4v, acc1);
        acc1 = fmaf(__int_as_float(q2.w), g5v, acc1);
        acc1 = fmaf(__int_as_float(q3.y), g6v, acc1);
        acc1 = fmaf(__int_as_float(q3.w), g7v, acc1);
    }
    acc0 = fmaxf(acc0, 0.0f);
    acc1 = fmaxf(acc1, 0.0f);
    if (br == 0) {
        hb[(size_t)r0 * 192 + c] = (_Float16)acc0;
        hb[(size_t)r1 * 192 + c] = (_Float16)acc1;
    } else {
        xb[(size_t)r0 * 128 + (size_t)(br - 1) * 64 + c] = (_Float16)acc0;
        xb[(size_t)r1 * 128 + (size_t)(br - 1) * 64 + c] = (_Float16)acc1;
    }
}

// hop1: y = A @ xb. Slab e.x = col*128; xb byte stride 256 -> off = (e.x<<1)+t2.
// One block (2 waves) per ROW PAIR. branch1 -> hb[:,64:128]; branch2 -> tmp.
__global__ void hop1_kernel(const int* __restrict__ fill, const int2* __restrict__ slab,
                            const _Float16* __restrict__ xb,
                            _Float16* __restrict__ hb, _Float16* __restrict__ tmp) {
    int bp = blockIdx.x;
    int r0 = 2 * bp, r1 = 2 * bp + 1;
    int t = threadIdx.x;        // 0..127
    float acc0 = 0.0f, acc1 = 0.0f;
    uint_t t2 = 2u * (uint_t)t;
    const int2* s0v = slab + (size_t)r0 * SLAB_A;
    const int2* s1v = slab + (size_t)r1 * SLAB_A;
    int f0 = min(fill[(size_t)r0 * FILL_STRIDE], SLAB_A);
    int f1 = min(fill[(size_t)r1 * FILL_STRIDE], SLAB_A);
    int e  = (max(f0, f1) + 7) & ~7;
    for (int j = 0; j < e; j += 8) {
        int4 p0 = *(const int4*)&s0v[j];
        int4 p1 = *(const int4*)&s0v[j + 2];
        int4 p2 = *(const int4*)&s0v[j + 4];
        int4 p3 = *(const int4*)&s0v[j + 6];
        int4 q0 = *(const int4*)&s1v[j];
        int4 q1 = *(const int4*)&s1v[j + 2];
        int4 q2 = *(const int4*)&s1v[j + 4];
        int4 q3 = *(const int4*)&s1v[j + 6];
        float f0v = h_at(xb, ((uint_t)p0.x << 1) + t2);
        float f1v = h_at(xb, ((uint_t)p0.z << 1) + t2);
        float f2v = h_at(xb, ((uint_t)p1.x << 1) + t2);
        float f3v = h_at(xb, ((uint_t)p1.z << 1) + t2);
        float f4v = h_at(xb, ((uint_t)p2.x << 1) + t2);
        float f5v = h_at(xb, ((uint_t)p2.z << 1) + t2);
        float f6v = h_at(xb, ((uint_t)p3.x << 1) + t2);
        float f7v = h_at(xb, ((uint_t)p3.z << 1) + t2);
        float g0v = h_at(xb, ((uint_t)q0.x << 1) + t2);
        float g1v = h_at(xb, ((uint_t)q0.z << 1) + t2);
        float g2v = h_at(xb, ((uint_t)q1.x << 1) + t2);
        float g3v = h_at(xb, ((uint_t)q1.z << 1) + t2);
        float g4v = h_at(xb, ((uint_t)q2.x << 1) + t2);
        float g5v = h_at(xb, ((uint_t)q2.z << 1) + t2);
        float g6v = h_at(xb, ((uint_t)q3.x << 1) + t2);
        float g7v = h_at(xb, ((uint_t)q3.z << 1) + t2);
        acc0 = fmaf(__int_as_float(p0.y), f0v, acc0);
        acc0 = fmaf(__int_as_float(p0.w), f1v, acc0);
        acc0 = fmaf(__int_as_float(p1.y), f2v, acc0);
        acc0 = fmaf(__int_as_float(p1.w), f3v, acc0);
        acc0 = fmaf(__int_as_float(p2.y), f4v, acc0);
        acc0 = fmaf(__int_as_float(p2.w), f5v, acc0);
        acc0 = fmaf(__int_as_float(p3.y), f6v, acc0);
        acc0 = fmaf(__int_as_float(p3.w), f7v, acc0);
        acc1 = fmaf(__int_as_float(q0.y), g0v, acc1);
        acc1 = fmaf(__int_as_float(q0.w), g1v, acc1);
        acc1 = fmaf(__int_as_float(q1.y), g2v, acc1);
        acc1 = fmaf(__int_as_float(q1.w), g3v, acc1);
        acc1 = fmaf(__int_as_float(q2.y), g4v, acc1);
        acc1 = fmaf(__int_as_float(q2.w), g5v, acc1);
        acc1 = fmaf(__int_as_float(q3.y), g6v, acc1);
        acc1 = fmaf(__int_as_float(q3.w), g7v, acc1);
    }
    if (t < 64) {
        hb[(size_t)r0 * 192 + 64 + t] = (_Float16)acc0;
        hb[(size_t)r1 * 192 + 64 + t] = (_Float16)acc1;
    } else {
        tmp[(size_t)r0 * 64 + (t - 64)] = (_Float16)acc0;
        tmp[(size_t)r1 * 64 + (t - 64)] = (_Float16)acc1;
    }
}

// hop2: branch2 second hop -> hb[:,128:192]. Slab e.x = col*128 = tmp byte off.
__global__ void hop2_kernel(const int* __restrict__ fill, const int2* __restrict__ slab,
                            const _Float16* __restrict__ tmp, _Float16* __restrict__ hb) {
    int bp = blockIdx.x;
    int r0 = 2 * bp, r1 = 2 * bp + 1;
    int t = threadIdx.x;        // 0..63
    float acc0 = 0.0f, acc1 = 0.0f;
    uint_t t2 = 2u * (uint_t)t;
    const int2* s0v = slab + (size_t)r0 * SLAB_A;
    const int2* s1v = slab + (size_t)r1 * SLAB_A;
    int f0 = min(fill[(size_t)r0 * FILL_STRIDE], SLAB_A);
    int f1 = min(fill[(size_t)r1 * FILL_STRIDE], SLAB_A);
    int e  = (max(f0, f1) + 7) & ~7;
    for (int j = 0; j < e; j += 8) {
        int4 p0 = *(const int4*)&s0v[j];
        int4 p1 = *(const int4*)&s0v[j + 2];
        int4 p2 = *(const int4*)&s0v[j + 4];
        int4 p3 = *(const int4*)&s0v[j + 6];
        int4 q0 = *(const int4*)&s1v[j];
        int4 q1 = *(const int4*)&s1v[j + 2];
        int4 q2 = *(const int4*)&s1v[j + 4];
        int4 q3 = *(const int4*)&s1v[j + 6];
        float f0v = h_at(tmp, (uint_t)p0.x + t2);
        float f1v = h_at(tmp, (uint_t)p0.z + t2);
        float f2v = h_at(tmp, (uint_t)p1.x + t2);
        float f3v = h_at(tmp, (uint_t)p1.z + t2);
        float f4v = h_at(tmp, (uint_t)p2.x + t2);
        float f5v = h_at(tmp, (uint_t)p2.z + t2);
        float f6v = h_at(tmp, (uint_t)p3.x + t2);
        float f7v = h_at(tmp, (uint_t)p3.z + t2);
        float g0v = h_at(tmp, (uint_t)q0.x + t2);
        float g1v = h_at(tmp, (uint_t)q0.z + t2);
        float g2v = h_at(tmp, (uint_t)q1.x + t2);
        float g3v = h_at(tmp, (uint_t)q1.z + t2);
        float g4v = h_at(tmp, (uint_t)q2.x + t2);
        float g5v = h_at(tmp, (uint_t)q2.z + t2);
        float g6v = h_at(tmp, (uint_t)q3.x + t2);
        float g7v = h_at(tmp, (uint_t)q3.z + t2);
        acc0 = fmaf(__int_as_float(p0.y), f0v, acc0);
        acc0 = fmaf(__int_as_float(p0.w), f1v, acc0);
        acc0 = fmaf(__int_as_float(p1.y), f2v, acc0);
        acc0 = fmaf(__int_as_float(p1.w), f3v, acc0);
        acc0 = fmaf(__int_as_float(p2.y), f4v, acc0);
        acc0 = fmaf(__int_as_float(p2.w), f5v, acc0);
        acc0 = fmaf(__int_as_float(p3.y), f6v, acc0);
        acc0 = fmaf(__int_as_float(p3.w), f7v, acc0);
        acc1 = fmaf(__int_as_float(q0.y), g0v, acc1);
        acc1 = fmaf(__int_as_float(q0.w), g1v, acc1);
        acc1 = fmaf(__int_as_float(q1.y), g2v, acc1);
        acc1 = fmaf(__int_as_float(q1.w), g3v, acc1);
        acc1 = fmaf(__int_as_float(q2.y), g4v, acc1);
        acc1 = fmaf(__int_as_float(q2.w), g5v, acc1);
        acc1 = fmaf(__int_as_float(q3.y), g6v, acc1);
        acc1 = fmaf(__int_as_float(q3.w), g7v, acc1);
    }
    hb[(size_t)r0 * 192 + 128 + t] = (_Float16)acc0;
    hb[(size_t)r1 * 192 + 128 + t] = (_Float16)acc1;
}

// ---------------------------------------------------------------------------
// FC + log_softmax via MFMA (f16). Block = 3 waves; wave nt owns 16 cols;
// 16 rows per block; K=192 = 6 x mfma_f32_16x16x32_f16.
// ---------------------------------------------------------------------------
__global__ void fc_mfma_kernel(const _Float16* __restrict__ hb,
                               const _Float16* __restrict__ fcwB,
                               const float* __restrict__ fc_b,
                               float* __restrict__ out) {
    int wave = threadIdx.x >> 6;      // 0..2 = N-tile
    int lane = threadIdx.x & 63;
    int m16  = lane & 15;
    int quad = lane >> 4;
    size_t rowbase = (size_t)blockIdx.x * 16;

    float4v acc = {0.f, 0.f, 0.f, 0.f};
    const _Float16* arow = hb   + (rowbase + m16) * 192 + quad * 8;
    const _Float16* brow = fcwB + (size_t)(wave * 16 + m16) * 192 + quad * 8;
#pragma unroll
    for (int s = 0; s < 6; ++s) {
        half8v a = *(const half8v*)(arow + s * 32);
        half8v b = *(const half8v*)(brow + s * 32);
        acc = __builtin_amdgcn_mfma_f32_16x16x32_f16(a, b, acc, 0, 0, 0);
    }

    __shared__ float lds[16][49];     // 48 cols + pad
    __shared__ float s_lse[16];
    int col = wave * 16 + m16;
    float bias = (col < NCLS) ? fc_b[col] : 0.0f;
#pragma unroll
    for (int i = 0; i < 4; ++i) {
        lds[quad * 4 + i][col] = acc[i] + bias;
    }
    __syncthreads();
    if (threadIdx.x < 16) {
        int row = threadIdx.x;
        float m = -INFINITY;
        for (int c = 0; c < NCLS; ++c) m = fmaxf(m, lds[row][c]);
        float s = 0.0f;
        for (int c = 0; c < NCLS; ++c) s += expf(lds[row][c] - m);
        s_lse[row] = m + logf(s);
    }
    __syncthreads();
    for (int idx = threadIdx.x; idx < 16 * NCLS; idx += 192) {
        int row = idx / NCLS, c = idx - row * NCLS;
        out[(rowbase + row) * NCLS + c] = lds[row][c] - s_lse[row];
    }
}

// ---------------------------------------------------------------------------

extern "C" void kernel_launch(void* const* d_in, const int* in_sizes, int n_in,
                              void* d_out, int out_size, void* d_ws, size_t ws_size,
                              hipStream_t stream) {
    const int*   adj_idx  = (const int*)  d_in[0];
    const float* adj_val  = (const float*)d_in[1];
    const int*   feat_idx = (const int*)  d_in[2];
    const float* feat_val = (const float*)d_in[3];
    const float* w1 = (const float*)d_in[4];
    const float* b1 = (const float*)d_in[5];
    const float* w2 = (const float*)d_in[6];
    const float* b2 = (const float*)d_in[7];
    const float* w3 = (const float*)d_in[8];
    const float* b3 = (const float*)d_in[9];
    const float* fc_w = (const float*)d_in[10];
    const float* fc_b = (const float*)d_in[11];
    float* out = (float*)d_out;

    char* ws = (char*)d_ws;
    size_t off = 0;
    auto take = [&](size_t bytes) -> char* {
        char* p = ws + off;
        off = (off + bytes + 255) & ~(size_t)255;
        return p;
    };
    // fills region: [featFill | adjFill | bfF(256) | bfA(256)] -- one memset.
    int*  fills    = (int*)take(((size_t)2 * N_NODES * FILL_STRIDE + 512) * sizeof(int));
    int*  featFill = fills;
    int*  adjFill  = fills + (size_t)N_NODES * FILL_STRIDE;
    int*  bfF      = fills + (size_t)2 * N_NODES * FILL_STRIDE;
    int*  bfA      = bfF + 256;
    int2* featSlab = (int2*)take((size_t)N_NODES * SLAB_F * sizeof(int2));        // 32 MB
    int2* adjSlab  = (int2*)take((size_t)N_NODES * SLAB_A * sizeof(int2));        // 19.2 MB
    _Float16* wcat = (_Float16*)take((size_t)F_IN * 192 * sizeof(_Float16));      // 0.79 MB
    _Float16* fcwB = (_Float16*)take((size_t)48 * 192 * sizeof(_Float16));        // 18 KB
    _Float16* xb   = (_Float16*)take((size_t)N_NODES * 128 * sizeof(_Float16));   // 12.8 MB
    _Float16* hb   = (_Float16*)take((size_t)N_NODES * 192 * sizeof(_Float16));   // 19.2 MB
    // Aliases (no new workspace -- total stays at the proven ~90.4 MB):
    //   barrF (14.5 MB) -> hb (19.2 MB): dead once bscatter completes.
    //   barrA ( 7.5 MB) -> xb (12.8 MB): dead once bscatter completes.
    //   tmp   ( 6.4 MB) -> featSlab (32 MB): featSlab dead after spmm_feat.
    int2* barrF = (int2*)hb;
    int2* barrA = (int2*)xb;
    _Float16* tmp = (_Float16*)featSlab;

    hipMemsetAsync(fills, 0, ((size_t)2 * N_NODES * FILL_STRIDE + 512) * sizeof(int), stream);

    prep_kernel<<<(F_IN * HID + 48 * 192 + 255) / 256, 256, 0, stream>>>(
        w1, w2, w3, wcat, fc_w, fcwB);

    partition_kernel<<<FEAT_CHUNKS + ADJ_CHUNKS, 256, 0, stream>>>(
        feat_idx, feat_val, adj_idx, adj_val, bfF, barrF, bfA, barrA);

    bscatter_kernel<<<2 * NBUCK * QPB, 256, 0, stream>>>(
        bfF, barrF, bfA, barrA, featFill, featSlab, adjFill, adjSlab);

    spmm_feat_kernel<<<N_NODES / 2, 192, 0, stream>>>(featFill, featSlab, wcat,
                                                      b1, b2, b3, hb, xb);
    hop1_kernel<<<N_NODES / 2, 128, 0, stream>>>(adjFill, adjSlab, xb, hb, tmp);
    hop2_kernel<<<N_NODES / 2, 64, 0, stream>>>(adjFill, adjSlab, tmp, hb);
    fc_mfma_kernel<<<N_NODES / 16, 192, 0, stream>>>(hb, fcwB, fc_b, out);
}

// Round 11
// 254.651 us; speedup vs baseline: 1.3299x; 1.0163x over previous
//
#include <hip/hip_runtime.h>
#include <math.h>

#define N_NODES   50000
#define F_IN      2048
#define E_ADJ     800000
#define NNZ_FEAT  1600000
#define HID       64
#define NCLS      40

// Fixed-capacity per-row slabs (degrees Poisson(32)/Poisson(16), max ~58/~35).
#define SLAB_F    80    // 640 B / row (multiple of 8)
#define SLAB_A    48    // 384 B / row (multiple of 8)

// One fill counter per 64B cache line.
#define FILL_STRIDE 16

// Radix-partition geometry: buckets are now 64 rows directly (round 10 used
// 256-row buckets + 4 quarter-blocks, which re-read each bucket 4x = 76.8MB).
#define RPB       64
#define NBUCK     784                       // ceil(50000/64)
#define BCAP_F    2368                      // Poisson(2048) +7 sigma
#define BCAP_A    1248                      // Poisson(1024) +7 sigma
#define IPT       8
#define CHUNK_ITEMS (256 * IPT)             // 2048
#define FEAT_CHUNKS ((NNZ_FEAT + CHUNK_ITEMS - 1) / CHUNK_ITEMS)   // 782
#define ADJ_CHUNKS  ((E_ADJ  + CHUNK_ITEMS - 1) / CHUNK_ITEMS)     // 391

// WORKSPACE: stays at the proven ~90.4 MB. barrF(14.2MB)->hb(19.2MB),
// barrA(7.5MB)->xb(12.8MB) (dead before spmm_feat writes them);
// tmp->featSlab (dead after spmm_feat).

typedef unsigned short ushort_t;
typedef unsigned int   uint_t;
typedef _Float16 half8v __attribute__((ext_vector_type(8)));
typedef float    float4v __attribute__((ext_vector_type(4)));

// ---------------------------------------------------------------------------
// PASS 1: partition COO items into per-bucket (64-row) append arrays.
// Per block: LDS bucket counts -> parallel Hillis-Steele scan (784 buckets;
// round 10's t==0 serial scan would be 784 iters) -> one global atomic per
// touched bucket -> LDS bucket-major staging -> coalesced writes.
// Entry: x = (col<<6)|rowInBucket, y = fp32 value bits.
// ---------------------------------------------------------------------------
__global__ void partition_kernel(const int* __restrict__ fi, const float* __restrict__ fv,
                                 const int* __restrict__ ai, const float* __restrict__ av,
                                 int* __restrict__ bfF, int2* __restrict__ barrF,
                                 int* __restrict__ bfA, int2* __restrict__ barrA) {
    __shared__ int  cnt[NBUCK];
    __shared__ int  scan[NBUCK];
    __shared__ int  gbase[NBUCK];
    __shared__ int  tsum[256];
    __shared__ int  totalS;
    __shared__ int2 sItem[CHUNK_ITEMS];
    __shared__ int  sDst[CHUNK_ITEMS];

    int bid = blockIdx.x;
    bool isF = bid < FEAT_CHUNKS;
    const int* rows; const int* cols; const float* vals;
    int n, chunk, bcap; int* bfill; int2* barr;
    if (isF) { rows = fi; cols = fi + NNZ_FEAT; vals = fv; n = NNZ_FEAT;
               bfill = bfF; barr = barrF; bcap = BCAP_F; chunk = bid; }
    else     { rows = ai; cols = ai + E_ADJ;   vals = av; n = E_ADJ;
               bfill = bfA; barr = barrA; bcap = BCAP_A; chunk = bid - FEAT_CHUNKS; }

    int t = threadIdx.x;
    for (int i = t; i < NBUCK; i += 256) cnt[i] = 0;
    __syncthreads();

    int ibase = chunk * CHUNK_ITEMS + t;
    int rr[IPT], cc[IPT], bk[IPT], sl[IPT]; float vv[IPT];
#pragma unroll
    for (int k = 0; k < IPT; ++k) {
        int i = ibase + k * 256;
        bk[k] = -1;
        if (i < n) {
            rr[k] = rows[i]; cc[k] = cols[i]; vv[k] = vals[i];
            bk[k] = rr[k] >> 6;                       // RPB = 64
            sl[k] = atomicAdd(&cnt[bk[k]], 1);
        }
    }
    __syncthreads();

    // Parallel exclusive scan over 784 buckets: 4 buckets/thread local sums,
    // Hillis-Steele inclusive scan over the 256 thread sums, local expand.
    int ls = 0;
    if (t < 196) {
        int b0 = 4 * t;
        ls = cnt[b0] + cnt[b0 + 1] + cnt[b0 + 2] + cnt[b0 + 3];
    }
    tsum[t] = ls;
    __syncthreads();
    for (int d = 1; d < 256; d <<= 1) {
        int v = (t >= d) ? tsum[t - d] : 0;
        __syncthreads();
        tsum[t] += v;
        __syncthreads();
    }
    if (t == 0) totalS = tsum[255];
    if (t < 196) {
        int base = (t == 0) ? 0 : tsum[t - 1];
        int b0 = 4 * t;
        scan[b0]     = base;
        scan[b0 + 1] = scan[b0]     + cnt[b0];
        scan[b0 + 2] = scan[b0 + 1] + cnt[b0 + 1];
        scan[b0 + 3] = scan[b0 + 2] + cnt[b0 + 2];
    }
    __syncthreads();
    for (int b = t; b < NBUCK; b += 256)
        gbase[b] = cnt[b] ? atomicAdd(&bfill[b], cnt[b]) : 0;
    __syncthreads();

#pragma unroll
    for (int k = 0; k < IPT; ++k) {
        if (bk[k] >= 0) {
            int pos = scan[bk[k]] + sl[k];             // block-local bucket-major
            int gp  = gbase[bk[k]] + sl[k];            // position in bucket array
            int2 e; e.x = (cc[k] << 6) | (rr[k] & 63); e.y = __float_as_int(vv[k]);
            sItem[pos] = e;
            sDst[pos]  = (gp < bcap) ? (bk[k] * bcap + gp) : -1;
        }
    }
    __syncthreads();

    int total = totalS;
    for (int j = t; j < total; j += 256) {             // coalesced: runs are contiguous
        int d = sDst[j];
        if (d >= 0) barr[d] = sItem[j];
    }
}

// ---------------------------------------------------------------------------
// PASS 2: atomic-free per-bucket scatter. One block per 64-row bucket; reads
// EXACTLY its own items (round 10 read each bucket 4x). Zero LDS staging
// (doubles as slab zero-padding) -> LDS-atomic per-row offsets -> plain-store
// fills -> copy-out TRIMMED to roundup8(pair max) (round 10 wrote full cap:
// 51.2 MB; this writes ~21 MB). No global atomics.
// Slab entry: x = pre-scaled byte offset (col*stride), y = value bits.
// ---------------------------------------------------------------------------
__global__ void bscatter_kernel(const int* __restrict__ bfF, const int2* __restrict__ barrF,
                                const int* __restrict__ bfA, const int2* __restrict__ barrA,
                                int* __restrict__ featFill, int2* __restrict__ featSlab,
                                int* __restrict__ adjFill,  int2* __restrict__ adjSlab) {
    __shared__ int2 stage[RPB * SLAB_F];       // 40 KB (feat); adj uses prefix
    __shared__ int  off[RPB];
    __shared__ int  tgt[RPB];

    int b = blockIdx.x;
    bool isF = b < NBUCK;
    int bb; const int* bf; const int2* barr; int bcap, cap, scale;
    int* fill; int2* slab;
    if (isF) { bb = b;         bf = bfF; barr = barrF; bcap = BCAP_F;
               fill = featFill; slab = featSlab; cap = SLAB_F; scale = 384; }
    else     { bb = b - NBUCK; bf = bfA; barr = barrA; bcap = BCAP_A;
               fill = adjFill;  slab = adjSlab;  cap = SLAB_A; scale = 128; }

    int rbase = bb * RPB;
    if (rbase >= N_NODES) return;
    int nrows = min(RPB, N_NODES - rbase);

    int t = threadIdx.x;
    int4* s4 = (int4*)stage;
    int nstage4 = RPB * cap / 2;
    for (int i = t; i < nstage4; i += 256) { int4 z = {0, 0, 0, 0}; s4[i] = z; }
    if (t < RPB) off[t] = 0;
    __syncthreads();

    int n = min(bf[bb], bcap);
    const int2* arr = barr + (size_t)bb * bcap;
    for (int i = t; i < n; i += 256) {
        int2 e = arr[i];
        int lr = e.x & 63;
        int p = atomicAdd(&off[lr], 1);        // LDS atomic
        if (p < cap) {
            int2 o; o.x = (e.x >> 6) * scale; o.y = e.y;
            stage[lr * cap + p] = o;
        }
    }
    __syncthreads();

    if (t < RPB) {
        int cf  = min(off[t], cap);
        int cfm = min(off[t ^ 1], cap);
        tgt[t] = (max(cf, cfm) + 7) & ~7;      // == gather kernels' pair bound
        if (t < nrows) fill[(size_t)(rbase + t) * FILL_STRIDE] = off[t];
    }
    __syncthreads();

    // Trimmed coalesced copy-out: 4 threads per row, int4 granularity.
    int row = t >> 2, l4 = t & 3;
    if (row < nrows) {
        const int4* srow = (const int4*)&stage[row * cap];
        int4* drow = (int4*)(slab + (size_t)(rbase + row) * cap);
        int m = tgt[row] >> 1;                 // int4 count (tgt multiple of 8)
        for (int i = l4; i < m; i += 4) drow[i] = srow[i];
    }
}

// Fused weight prep: w1|w2|w3 -> fp16 wcat[2048][192], and
// fc_w [192x40] -> class-major fp16 fcwB[48][192] (cols 40..47 zero).
__global__ void prep_kernel(const float* __restrict__ w1, const float* __restrict__ w2,
                            const float* __restrict__ w3, _Float16* __restrict__ wcat,
                            const float* __restrict__ fc_w, _Float16* __restrict__ fcwB) {
    int i = blockIdx.x * blockDim.x + threadIdx.x;
    if (i < F_IN * HID) {
        int f = i >> 6, c = i & 63;
        wcat[(size_t)f * 192 + c]       = (_Float16)w1[i];
        wcat[(size_t)f * 192 + 64 + c]  = (_Float16)w2[i];
        wcat[(size_t)f * 192 + 128 + c] = (_Float16)w3[i];
    } else {
        int j = i - F_IN * HID;
        if (j < 48 * 192) {
            int c = j / 192, k = j - c * 192;
            fcwB[j] = (c < NCLS) ? (_Float16)fc_w[k * NCLS + c] : (_Float16)0.0f;
        }
    }
}

static __device__ inline float h_at(const void* base, uint_t byteoff) {
    return (float)*(const _Float16*)((const char*)base + byteoff);
}

// ---------------------------------------------------------------------------
// SpMM feat @ wcat + bias, relu. One block (3 waves) per ROW PAIR; thread t
// owns output col t of 192 for BOTH rows -> two independent gather streams.
// (Round-6 proven form; rounds 1-5 established ~52us floor for this phase.)
// Branch0 -> hb[:,0:64]; br 1,2 -> xb[N,128].
// ---------------------------------------------------------------------------
__global__ void spmm_feat_kernel(const int* __restrict__ fill, const int2* __restrict__ slab,
                                 const _Float16* __restrict__ wcat,
                                 const float* __restrict__ b1, const float* __restrict__ b2,
                                 const float* __restrict__ b3,
                                 _Float16* __restrict__ hb, _Float16* __restrict__ xb) {
    int bp = blockIdx.x;
    int r0 = 2 * bp, r1 = 2 * bp + 1;
    int t  = threadIdx.x;       // 0..191
    int br = t >> 6;
    int c  = t & 63;
    const float* b = (br == 0) ? b1 : (br == 1) ? b2 : b3;
    float bias = b[c];
    float acc0 = bias, acc1 = bias;
    uint_t t2 = 2u * (uint_t)t;
    const int2* s0v = slab + (size_t)r0 * SLAB_F;
    const int2* s1v = slab + (size_t)r1 * SLAB_F;
    int f0 = min(fill[(size_t)r0 * FILL_STRIDE], SLAB_F);
    int f1 = min(fill[(size_t)r1 * FILL_STRIDE], SLAB_F);
    int e  = (max(f0, f1) + 7) & ~7;
    for (int j = 0; j < e; j += 8) {
        int4 p0 = *(const int4*)&s0v[j];
        int4 p1 = *(const int4*)&s0v[j + 2];
        int4 p2 = *(const int4*)&s0v[j + 4];
        int4 p3 = *(const int4*)&s0v[j + 6];
        int4 q0 = *(const int4*)&s1v[j];
        int4 q1 = *(const int4*)&s1v[j + 2];
        int4 q2 = *(const int4*)&s1v[j + 4];
        int4 q3 = *(const int4*)&s1v[j + 6];
        float f0v = h_at(wcat, (uint_t)p0.x + t2);
        float f1v = h_at(wcat, (uint_t)p0.z + t2);
        float f2v = h_at(wcat, (uint_t)p1.x + t2);
        float f3v = h_at(wcat, (uint_t)p1.z + t2);
        float f4v = h_at(wcat, (uint_t)p2.x + t2);
        float f5v = h_at(wcat, (uint_t)p2.z + t2);
        float f6v = h_at(wcat, (uint_t)p3.x + t2);
        float f7v = h_at(wcat, (uint_t)p3.z + t2);
        float g0v = h_at(wcat, (uint_t)q0.x + t2);
        float g1v = h_at(wcat, (uint_t)q0.z + t2);
        float g2v = h_at(wcat, (uint_t)q1.x + t2);
        float g3v = h_at(wcat, (uint_t)q1.z + t2);
        float g4v = h_at(wcat, (uint_t)q2.x + t2);
        float g5v = h_at(wcat, (uint_t)q2.z + t2);
        float g6v = h_at(wcat, (uint_t)q3.x + t2);
        float g7v = h_at(wcat, (uint_t)q3.z + t2);
        acc0 = fmaf(__int_as_float(p0.y), f0v, acc0);
        acc0 = fmaf(__int_as_float(p0.w), f1v, acc0);
        acc0 = fmaf(__int_as_float(p1.y), f2v, acc0);
        acc0 = fmaf(__int_as_float(p1.w), f3v, acc0);
        acc0 = fmaf(__int_as_float(p2.y), f4v, acc0);
        acc0 = fmaf(__int_as_float(p2.w), f5v, acc0);
        acc0 = fmaf(__int_as_float(p3.y), f6v, acc0);
        acc0 = fmaf(__int_as_float(p3.w), f7v, acc0);
        acc1 = fmaf(__int_as_float(q0.y), g0v, acc1);
        acc1 = fmaf(__int_as_float(q0.w), g1v, acc1);
        acc1 = fmaf(__int_as_float(q1.y), g2v, acc1);
        acc1 = fmaf(__int_as_float(q1.w), g3v, acc1);
        acc1 = fmaf(__int_as_float(q2.y), g4v, acc1);
        acc1 = fmaf(__int_as_float(q2.w), g5v, acc1);
        acc1 = fmaf(__int_as_float(q3.y), g6v, acc1);
        acc1 = fmaf(__int_as_float(q3.w), g7v, acc1);
    }
    acc0 = fmaxf(acc0, 0.0f);
    acc1 = fmaxf(acc1, 0.0f);
    if (br == 0) {
        hb[(size_t)r0 * 192 + c] = (_Float16)acc0;
        hb[(size_t)r1 * 192 + c] = (_Float16)acc1;
    } else {
        xb[(size_t)r0 * 128 + (size_t)(br - 1) * 64 + c] = (_Float16)acc0;
        xb[(size_t)r1 * 128 + (size_t)(br - 1) * 64 + c] = (_Float16)acc1;
    }
}

// hop1: y = A @ xb. Slab e.x = col*128; xb byte stride 256 -> off = (e.x<<1)+t2.
// One block (2 waves) per ROW PAIR. branch1 -> hb[:,64:128]; branch2 -> tmp.
__global__ void hop1_kernel(const int* __restrict__ fill, const int2* __restrict__ slab,
                            const _Float16* __restrict__ xb,
                            _Float16* __restrict__ hb, _Float16* __restrict__ tmp) {
    int bp = blockIdx.x;
    int r0 = 2 * bp, r1 = 2 * bp + 1;
    int t = threadIdx.x;        // 0..127
    float acc0 = 0.0f, acc1 = 0.0f;
    uint_t t2 = 2u * (uint_t)t;
    const int2* s0v = slab + (size_t)r0 * SLAB_A;
    const int2* s1v = slab + (size_t)r1 * SLAB_A;
    int f0 = min(fill[(size_t)r0 * FILL_STRIDE], SLAB_A);
    int f1 = min(fill[(size_t)r1 * FILL_STRIDE], SLAB_A);
    int e  = (max(f0, f1) + 7) & ~7;
    for (int j = 0; j < e; j += 8) {
        int4 p0 = *(const int4*)&s0v[j];
        int4 p1 = *(const int4*)&s0v[j + 2];
        int4 p2 = *(const int4*)&s0v[j + 4];
        int4 p3 = *(const int4*)&s0v[j + 6];
        int4 q0 = *(const int4*)&s1v[j];
        int4 q1 = *(const int4*)&s1v[j + 2];
        int4 q2 = *(const int4*)&s1v[j + 4];
        int4 q3 = *(const int4*)&s1v[j + 6];
        float f0v = h_at(xb, ((uint_t)p0.x << 1) + t2);
        float f1v = h_at(xb, ((uint_t)p0.z << 1) + t2);
        float f2v = h_at(xb, ((uint_t)p1.x << 1) + t2);
        float f3v = h_at(xb, ((uint_t)p1.z << 1) + t2);
        float f4v = h_at(xb, ((uint_t)p2.x << 1) + t2);
        float f5v = h_at(xb, ((uint_t)p2.z << 1) + t2);
        float f6v = h_at(xb, ((uint_t)p3.x << 1) + t2);
        float f7v = h_at(xb, ((uint_t)p3.z << 1) + t2);
        float g0v = h_at(xb, ((uint_t)q0.x << 1) + t2);
        float g1v = h_at(xb, ((uint_t)q0.z << 1) + t2);
        float g2v = h_at(xb, ((uint_t)q1.x << 1) + t2);
        float g3v = h_at(xb, ((uint_t)q1.z << 1) + t2);
        float g4v = h_at(xb, ((uint_t)q2.x << 1) + t2);
        float g5v = h_at(xb, ((uint_t)q2.z << 1) + t2);
        float g6v = h_at(xb, ((uint_t)q3.x << 1) + t2);
        float g7v = h_at(xb, ((uint_t)q3.z << 1) + t2);
        acc0 = fmaf(__int_as_float(p0.y), f0v, acc0);
        acc0 = fmaf(__int_as_float(p0.w), f1v, acc0);
        acc0 = fmaf(__int_as_float(p1.y), f2v, acc0);
        acc0 = fmaf(__int_as_float(p1.w), f3v, acc0);
        acc0 = fmaf(__int_as_float(p2.y), f4v, acc0);
        acc0 = fmaf(__int_as_float(p2.w), f5v, acc0);
        acc0 = fmaf(__int_as_float(p3.y), f6v, acc0);
        acc0 = fmaf(__int_as_float(p3.w), f7v, acc0);
        acc1 = fmaf(__int_as_float(q0.y), g0v, acc1);
        acc1 = fmaf(__int_as_float(q0.w), g1v, acc1);
        acc1 = fmaf(__int_as_float(q1.y), g2v, acc1);
        acc1 = fmaf(__int_as_float(q1.w), g3v, acc1);
        acc1 = fmaf(__int_as_float(q2.y), g4v, acc1);
        acc1 = fmaf(__int_as_float(q2.w), g5v, acc1);
        acc1 = fmaf(__int_as_float(q3.y), g6v, acc1);
        acc1 = fmaf(__int_as_float(q3.w), g7v, acc1);
    }
    if (t < 64) {
        hb[(size_t)r0 * 192 + 64 + t] = (_Float16)acc0;
        hb[(size_t)r1 * 192 + 64 + t] = (_Float16)acc1;
    } else {
        tmp[(size_t)r0 * 64 + (t - 64)] = (_Float16)acc0;
        tmp[(size_t)r1 * 64 + (t - 64)] = (_Float16)acc1;
    }
}

// hop2: branch2 second hop -> hb[:,128:192]. Slab e.x = col*128 = tmp byte off.
__global__ void hop2_kernel(const int* __restrict__ fill, const int2* __restrict__ slab,
                            const _Float16* __restrict__ tmp, _Float16* __restrict__ hb) {
    int bp = blockIdx.x;
    int r0 = 2 * bp, r1 = 2 * bp + 1;
    int t = threadIdx.x;        // 0..63
    float acc0 = 0.0f, acc1 = 0.0f;
    uint_t t2 = 2u * (uint_t)t;
    const int2* s0v = slab + (size_t)r0 * SLAB_A;
    const int2* s1v = slab + (size_t)r1 * SLAB_A;
    int f0 = min(fill[(size_t)r0 * FILL_STRIDE], SLAB_A);
    int f1 = min(fill[(size_t)r1 * FILL_STRIDE], SLAB_A);
    int e  = (max(f0, f1) + 7) & ~7;
    for (int j = 0; j < e; j += 8) {
        int4 p0 = *(const int4*)&s0v[j];
        int4 p1 = *(const int4*)&s0v[j + 2];
        int4 p2 = *(const int4*)&s0v[j + 4];
        int4 p3 = *(const int4*)&s0v[j + 6];
        int4 q0 = *(const int4*)&s1v[j];
        int4 q1 = *(const int4*)&s1v[j + 2];
        int4 q2 = *(const int4*)&s1v[j + 4];
        int4 q3 = *(const int4*)&s1v[j + 6];
        float f0v = h_at(tmp, (uint_t)p0.x + t2);
        float f1v = h_at(tmp, (uint_t)p0.z + t2);
        float f2v = h_at(tmp, (uint_t)p1.x + t2);
        float f3v = h_at(tmp, (uint_t)p1.z + t2);
        float f4v = h_at(tmp, (uint_t)p2.x + t2);
        float f5v = h_at(tmp, (uint_t)p2.z + t2);
        float f6v = h_at(tmp, (uint_t)p3.x + t2);
        float f7v = h_at(tmp, (uint_t)p3.z + t2);
        float g0v = h_at(tmp, (uint_t)q0.x + t2);
        float g1v = h_at(tmp, (uint_t)q0.z + t2);
        float g2v = h_at(tmp, (uint_t)q1.x + t2);
        float g3v = h_at(tmp, (uint_t)q1.z + t2);
        float g4v = h_at(tmp, (uint_t)q2.x + t2);
        float g5v = h_at(tmp, (uint_t)q2.z + t2);
        float g6v = h_at(tmp, (uint_t)q3.x + t2);
        float g7v = h_at(tmp, (uint_t)q3.z + t2);
        acc0 = fmaf(__int_as_float(p0.y), f0v, acc0);
        acc0 = fmaf(__int_as_float(p0.w), f1v, acc0);
        acc0 = fmaf(__int_as_float(p1.y), f2v, acc0);
        acc0 = fmaf(__int_as_float(p1.w), f3v, acc0);
        acc0 = fmaf(__int_as_float(p2.y), f4v, acc0);
        acc0 = fmaf(__int_as_float(p2.w), f5v, acc0);
        acc0 = fmaf(__int_as_float(p3.y), f6v, acc0);
        acc0 = fmaf(__int_as_float(p3.w), f7v, acc0);
        acc1 = fmaf(__int_as_float(q0.y), g0v, acc1);
        acc1 = fmaf(__int_as_float(q0.w), g1v, acc1);
        acc1 = fmaf(__int_as_float(q1.y), g2v, acc1);
        acc1 = fmaf(__int_as_float(q1.w), g3v, acc1);
        acc1 = fmaf(__int_as_float(q2.y), g4v, acc1);
        acc1 = fmaf(__int_as_float(q2.w), g5v, acc1);
        acc1 = fmaf(__int_as_float(q3.y), g6v, acc1);
        acc1 = fmaf(__int_as_float(q3.w), g7v, acc1);
    }
    hb[(size_t)r0 * 192 + 128 + t] = (_Float16)acc0;
    hb[(size_t)r1 * 192 + 128 + t] = (_Float16)acc1;
}

// ---------------------------------------------------------------------------
// FC + log_softmax via MFMA (f16). Block = 3 waves; wave nt owns 16 cols;
// 16 rows per block; K=192 = 6 x mfma_f32_16x16x32_f16.
// ---------------------------------------------------------------------------
__global__ void fc_mfma_kernel(const _Float16* __restrict__ hb,
                               const _Float16* __restrict__ fcwB,
                               const float* __restrict__ fc_b,
                               float* __restrict__ out) {
    int wave = threadIdx.x >> 6;      // 0..2 = N-tile
    int lane = threadIdx.x & 63;
    int m16  = lane & 15;
    int quad = lane >> 4;
    size_t rowbase = (size_t)blockIdx.x * 16;

    float4v acc = {0.f, 0.f, 0.f, 0.f};
    const _Float16* arow = hb   + (rowbase + m16) * 192 + quad * 8;
    const _Float16* brow = fcwB + (size_t)(wave * 16 + m16) * 192 + quad * 8;
#pragma unroll
    for (int s = 0; s < 6; ++s) {
        half8v a = *(const half8v*)(arow + s * 32);
        half8v b = *(const half8v*)(brow + s * 32);
        acc = __builtin_amdgcn_mfma_f32_16x16x32_f16(a, b, acc, 0, 0, 0);
    }

    __shared__ float lds[16][49];     // 48 cols + pad
    __shared__ float s_lse[16];
    int col = wave * 16 + m16;
    float bias = (col < NCLS) ? fc_b[col] : 0.0f;
#pragma unroll
    for (int i = 0; i < 4; ++i) {
        lds[quad * 4 + i][col] = acc[i] + bias;
    }
    __syncthreads();
    if (threadIdx.x < 16) {
        int row = threadIdx.x;
        float m = -INFINITY;
        for (int c = 0; c < NCLS; ++c) m = fmaxf(m, lds[row][c]);
        float s = 0.0f;
        for (int c = 0; c < NCLS; ++c) s += expf(lds[row][c] - m);
        s_lse[row] = m + logf(s);
    }
    __syncthreads();
    for (int idx = threadIdx.x; idx < 16 * NCLS; idx += 192) {
        int row = idx / NCLS, c = idx - row * NCLS;
        out[(rowbase + row) * NCLS + c] = lds[row][c] - s_lse[row];
    }
}

// ---------------------------------------------------------------------------

extern "C" void kernel_launch(void* const* d_in, const int* in_sizes, int n_in,
                              void* d_out, int out_size, void* d_ws, size_t ws_size,
                              hipStream_t stream) {
    const int*   adj_idx  = (const int*)  d_in[0];
    const float* adj_val  = (const float*)d_in[1];
    const int*   feat_idx = (const int*)  d_in[2];
    const float* feat_val = (const float*)d_in[3];
    const float* w1 = (const float*)d_in[4];
    const float* b1 = (const float*)d_in[5];
    const float* w2 = (const float*)d_in[6];
    const float* b2 = (const float*)d_in[7];
    const float* w3 = (const float*)d_in[8];
    const float* b3 = (const float*)d_in[9];
    const float* fc_w = (const float*)d_in[10];
    const float* fc_b = (const float*)d_in[11];
    float* out = (float*)d_out;

    char* ws = (char*)d_ws;
    size_t off = 0;
    auto take = [&](size_t bytes) -> char* {
        char* p = ws + off;
        off = (off + bytes + 255) & ~(size_t)255;
        return p;
    };
    // fills region: [featFill | adjFill | bfF(1024) | bfA(1024)] -- one memset.
    int*  fills    = (int*)take(((size_t)2 * N_NODES * FILL_STRIDE + 2048) * sizeof(int));
    int*  featFill = fills;
    int*  adjFill  = fills + (size_t)N_NODES * FILL_STRIDE;
    int*  bfF      = fills + (size_t)2 * N_NODES * FILL_STRIDE;
    int*  bfA      = bfF + 1024;
    int2* featSlab = (int2*)take((size_t)N_NODES * SLAB_F * sizeof(int2));        // 32 MB
    int2* adjSlab  = (int2*)take((size_t)N_NODES * SLAB_A * sizeof(int2));        // 19.2 MB
    _Float16* wcat = (_Float16*)take((size_t)F_IN * 192 * sizeof(_Float16));      // 0.79 MB
    _Float16* fcwB = (_Float16*)take((size_t)48 * 192 * sizeof(_Float16));        // 18 KB
    _Float16* xb   = (_Float16*)take((size_t)N_NODES * 128 * sizeof(_Float16));   // 12.8 MB
    _Float16* hb   = (_Float16*)take((size_t)N_NODES * 192 * sizeof(_Float16));   // 19.2 MB
    // Aliases (no new workspace -- total stays at the proven ~90.4 MB):
    //   barrF (14.2 MB) -> hb (19.2 MB): dead once bscatter completes.
    //   barrA ( 7.5 MB) -> xb (12.8 MB): dead once bscatter completes.
    //   tmp   ( 6.4 MB) -> featSlab (32 MB): featSlab dead after spmm_feat.
    int2* barrF = (int2*)hb;
    int2* barrA = (int2*)xb;
    _Float16* tmp = (_Float16*)featSlab;

    hipMemsetAsync(fills, 0, ((size_t)2 * N_NODES * FILL_STRIDE + 2048) * sizeof(int), stream);

    prep_kernel<<<(F_IN * HID + 48 * 192 + 255) / 256, 256, 0, stream>>>(
        w1, w2, w3, wcat, fc_w, fcwB);

    partition_kernel<<<FEAT_CHUNKS + ADJ_CHUNKS, 256, 0, stream>>>(
        feat_idx, feat_val, adj_idx, adj_val, bfF, barrF, bfA, barrA);

    bscatter_kernel<<<2 * NBUCK, 256, 0, stream>>>(
        bfF, barrF, bfA, barrA, featFill, featSlab, adjFill, adjSlab);

    spmm_feat_kernel<<<N_NODES / 2, 192, 0, stream>>>(featFill, featSlab, wcat,
                                                      b1, b2, b3, hb, xb);
    hop1_kernel<<<N_NODES / 2, 128, 0, stream>>>(adjFill, adjSlab, xb, hb, tmp);
    hop2_kernel<<<N_NODES / 2, 64, 0, stream>>>(adjFill, adjSlab, tmp, hb);
    fc_mfma_kernel<<<N_NODES / 16, 192, 0, stream>>>(hb, fcwB, fc_b, out);
}

// Round 12
// 242.002 us; speedup vs baseline: 1.3994x; 1.0523x over previous
//
#include <hip/hip_runtime.h>
#include <math.h>

#define N_NODES   50000
#define F_IN      2048
#define E_ADJ     800000
#define NNZ_FEAT  1600000
#define HID       64
#define NCLS      40

// Fixed-capacity per-row slabs (degrees Poisson(32)/Poisson(16), max ~58/~35).
#define SLAB_F    80    // 640 B / row (multiple of 8)
#define SLAB_A    48    // 384 B / row (multiple of 8)

// Radix-partition geometry: 64-row buckets.
#define RPB       64
#define NBUCK     784                       // ceil(50000/64)
#define BCAP_F    2368                      // Poisson(2048) +7 sigma
#define BCAP_A    1248                      // Poisson(1024) +7 sigma
// IPT 16 (was 8): scatter runs double to ~5.2 entries -> ~45% fewer
// partial-line write touches in the bucket arrays.
#define IPT       16
#define CHUNK_ITEMS (256 * IPT)             // 4096
#define FEAT_CHUNKS ((NNZ_FEAT + CHUNK_ITEMS - 1) / CHUNK_ITEMS)   // 391
#define ADJ_CHUNKS  ((E_ADJ  + CHUNK_ITEMS - 1) / CHUNK_ITEMS)     // 196
#define PREP_ITEMS  (F_IN * HID + 48 * 192)
#define PREP_BLOCKS ((PREP_ITEMS + 255) / 256)                     // 548

// WORKSPACE: ~84 MB (under the proven ~90.4 MB). barrF(14.2MB)->hb(19.2MB),
// barrA(7.5MB)->xb(12.8MB) (dead before spmm_feat writes them);
// tmp->featSlab (dead after spmm_feat).

typedef unsigned short ushort_t;
typedef unsigned int   uint_t;
typedef _Float16 half8v __attribute__((ext_vector_type(8)));
typedef float    float4v __attribute__((ext_vector_type(4)));

// ---------------------------------------------------------------------------
// PASS 1 (+ fused weight prep): partition COO items into per-bucket (64-row)
// append arrays. Per block: LDS bucket counts -> parallel Hillis-Steele scan
// -> one global atomic per touched bucket -> LDS bucket-major staging ->
// coalesced writes. Entry: x = (col<<6)|rowInBucket, y = fp32 value bits.
// Blocks past the partition range do prep (wcat/fcwB) -- fusing the
// independent prep dispatch into this one.
// ---------------------------------------------------------------------------
__global__ void partition_prep_kernel(const int* __restrict__ fi, const float* __restrict__ fv,
                                      const int* __restrict__ ai, const float* __restrict__ av,
                                      int* __restrict__ bfF, int2* __restrict__ barrF,
                                      int* __restrict__ bfA, int2* __restrict__ barrA,
                                      const float* __restrict__ w1, const float* __restrict__ w2,
                                      const float* __restrict__ w3, _Float16* __restrict__ wcat,
                                      const float* __restrict__ fc_w, _Float16* __restrict__ fcwB) {
    __shared__ int  cnt[NBUCK];
    __shared__ int  scan[NBUCK];
    __shared__ int  gbase[NBUCK];
    __shared__ int  tsum[256];
    __shared__ int  totalS;
    __shared__ int2 sItem[CHUNK_ITEMS];
    __shared__ int  sDst[CHUNK_ITEMS];

    int bid = blockIdx.x;
    if (bid >= FEAT_CHUNKS + ADJ_CHUNKS) {
        // ---- fused prep ----
        int i = (bid - FEAT_CHUNKS - ADJ_CHUNKS) * 256 + threadIdx.x;
        if (i < F_IN * HID) {
            int f = i >> 6, c = i & 63;
            wcat[(size_t)f * 192 + c]       = (_Float16)w1[i];
            wcat[(size_t)f * 192 + 64 + c]  = (_Float16)w2[i];
            wcat[(size_t)f * 192 + 128 + c] = (_Float16)w3[i];
        } else {
            int j = i - F_IN * HID;
            if (j < 48 * 192) {
                int c = j / 192, k = j - c * 192;
                fcwB[j] = (c < NCLS) ? (_Float16)fc_w[k * NCLS + c] : (_Float16)0.0f;
            }
        }
        return;
    }

    bool isF = bid < FEAT_CHUNKS;
    const int* rows; const int* cols; const float* vals;
    int n, chunk, bcap; int* bfill; int2* barr;
    if (isF) { rows = fi; cols = fi + NNZ_FEAT; vals = fv; n = NNZ_FEAT;
               bfill = bfF; barr = barrF; bcap = BCAP_F; chunk = bid; }
    else     { rows = ai; cols = ai + E_ADJ;   vals = av; n = E_ADJ;
               bfill = bfA; barr = barrA; bcap = BCAP_A; chunk = bid - FEAT_CHUNKS; }

    int t = threadIdx.x;
    for (int i = t; i < NBUCK; i += 256) cnt[i] = 0;
    __syncthreads();

    int ibase = chunk * CHUNK_ITEMS + t;
    int rr[IPT], cc[IPT], bk[IPT], sl[IPT]; float vv[IPT];
#pragma unroll
    for (int k = 0; k < IPT; ++k) {
        int i = ibase + k * 256;
        bk[k] = -1;
        if (i < n) {
            rr[k] = rows[i]; cc[k] = cols[i]; vv[k] = vals[i];
            bk[k] = rr[k] >> 6;                       // RPB = 64
            sl[k] = atomicAdd(&cnt[bk[k]], 1);
        }
    }
    __syncthreads();

    // Parallel exclusive scan over 784 buckets.
    int ls = 0;
    if (t < 196) {
        int b0 = 4 * t;
        ls = cnt[b0] + cnt[b0 + 1] + cnt[b0 + 2] + cnt[b0 + 3];
    }
    tsum[t] = ls;
    __syncthreads();
    for (int d = 1; d < 256; d <<= 1) {
        int v = (t >= d) ? tsum[t - d] : 0;
        __syncthreads();
        tsum[t] += v;
        __syncthreads();
    }
    if (t == 0) totalS = tsum[255];
    if (t < 196) {
        int base = (t == 0) ? 0 : tsum[t - 1];
        int b0 = 4 * t;
        scan[b0]     = base;
        scan[b0 + 1] = scan[b0]     + cnt[b0];
        scan[b0 + 2] = scan[b0 + 1] + cnt[b0 + 1];
        scan[b0 + 3] = scan[b0 + 2] + cnt[b0 + 2];
    }
    __syncthreads();
    for (int b = t; b < NBUCK; b += 256)
        gbase[b] = cnt[b] ? atomicAdd(&bfill[b], cnt[b]) : 0;
    __syncthreads();

#pragma unroll
    for (int k = 0; k < IPT; ++k) {
        if (bk[k] >= 0) {
            int pos = scan[bk[k]] + sl[k];             // block-local bucket-major
            int gp  = gbase[bk[k]] + sl[k];            // position in bucket array
            int2 e; e.x = (cc[k] << 6) | (rr[k] & 63); e.y = __float_as_int(vv[k]);
            sItem[pos] = e;
            sDst[pos]  = (gp < bcap) ? (bk[k] * bcap + gp) : -1;
        }
    }
    __syncthreads();

    int total = totalS;
    for (int j = t; j < total; j += 256) {             // coalesced: runs are contiguous
        int d = sDst[j];
        if (d >= 0) barr[d] = sItem[j];
    }
}

// ---------------------------------------------------------------------------
// PASS 2: atomic-free per-bucket scatter. One block per 64-row bucket; reads
// exactly its own items. Zero LDS staging (doubles as slab zero-padding) ->
// LDS-atomic per-row offsets -> coalesced dense fill stores -> copy-out
// trimmed to roundup8(pair max). No global atomics.
// Slab entry: x = pre-scaled byte offset (col*stride), y = value bits.
// ---------------------------------------------------------------------------
__global__ void bscatter_kernel(const int* __restrict__ bfF, const int2* __restrict__ barrF,
                                const int* __restrict__ bfA, const int2* __restrict__ barrA,
                                int* __restrict__ featFill, int2* __restrict__ featSlab,
                                int* __restrict__ adjFill,  int2* __restrict__ adjSlab) {
    __shared__ int2 stage[RPB * SLAB_F];       // 40 KB (feat); adj uses prefix
    __shared__ int  off[RPB];
    __shared__ int  tgt[RPB];

    int b = blockIdx.x;
    bool isF = b < NBUCK;
    int bb; const int* bf; const int2* barr; int bcap, cap, scale;
    int* fill; int2* slab;
    if (isF) { bb = b;         bf = bfF; barr = barrF; bcap = BCAP_F;
               fill = featFill; slab = featSlab; cap = SLAB_F; scale = 384; }
    else     { bb = b - NBUCK; bf = bfA; barr = barrA; bcap = BCAP_A;
               fill = adjFill;  slab = adjSlab;  cap = SLAB_A; scale = 128; }

    int rbase = bb * RPB;
    if (rbase >= N_NODES) return;
    int nrows = min(RPB, N_NODES - rbase);

    int t = threadIdx.x;
    int4* s4 = (int4*)stage;
    int nstage4 = RPB * cap / 2;
    for (int i = t; i < nstage4; i += 256) { int4 z = {0, 0, 0, 0}; s4[i] = z; }
    if (t < RPB) off[t] = 0;
    __syncthreads();

    int n = min(bf[bb], bcap);
    const int2* arr = barr + (size_t)bb * bcap;
    for (int i = t; i < n; i += 256) {
        int2 e = arr[i];
        int lr = e.x & 63;
        int p = atomicAdd(&off[lr], 1);        // LDS atomic
        if (p < cap) {
            int2 o; o.x = (e.x >> 6) * scale; o.y = e.y;
            stage[lr * cap + p] = o;
        }
    }
    __syncthreads();

    if (t < RPB) {
        int cf  = min(off[t], cap);
        int cfm = min(off[t ^ 1], cap);
        tgt[t] = (max(cf, cfm) + 7) & ~7;      // == gather kernels' pair bound
        if (t < nrows) fill[rbase + t] = off[t];   // dense, coalesced
    }
    __syncthreads();

    // Trimmed coalesced copy-out: 4 threads per row, int4 granularity.
    int row = t >> 2, l4 = t & 3;
    if (row < nrows) {
        const int4* srow = (const int4*)&stage[row * cap];
        int4* drow = (int4*)(slab + (size_t)(rbase + row) * cap);
        int m = tgt[row] >> 1;                 // int4 count (tgt multiple of 8)
        for (int i = l4; i < m; i += 4) drow[i] = srow[i];
    }
}

static __device__ inline float h_at(const void* base, uint_t byteoff) {
    return (float)*(const _Float16*)((const char*)base + byteoff);
}

// ---------------------------------------------------------------------------
// SpMM feat @ wcat + bias, relu. One block (3 waves) per ROW PAIR; thread t
// owns output col t of 192 for BOTH rows -> two independent gather streams.
// (Proven form; rounds 1-5 established ~52us floor for this phase.)
// Branch0 -> hb[:,0:64]; br 1,2 -> xb[N,128].
// ---------------------------------------------------------------------------
__global__ void spmm_feat_kernel(const int* __restrict__ fill, const int2* __restrict__ slab,
                                 const _Float16* __restrict__ wcat,
                                 const float* __restrict__ b1, const float* __restrict__ b2,
                                 const float* __restrict__ b3,
                                 _Float16* __restrict__ hb, _Float16* __restrict__ xb) {
    int bp = blockIdx.x;
    int r0 = 2 * bp, r1 = 2 * bp + 1;
    int t  = threadIdx.x;       // 0..191
    int br = t >> 6;
    int c  = t & 63;
    const float* b = (br == 0) ? b1 : (br == 1) ? b2 : b3;
    float bias = b[c];
    float acc0 = bias, acc1 = bias;
    uint_t t2 = 2u * (uint_t)t;
    const int2* s0v = slab + (size_t)r0 * SLAB_F;
    const int2* s1v = slab + (size_t)r1 * SLAB_F;
    int f0 = min(fill[r0], SLAB_F);
    int f1 = min(fill[r1], SLAB_F);
    int e  = (max(f0, f1) + 7) & ~7;
    for (int j = 0; j < e; j += 8) {
        int4 p0 = *(const int4*)&s0v[j];
        int4 p1 = *(const int4*)&s0v[j + 2];
        int4 p2 = *(const int4*)&s0v[j + 4];
        int4 p3 = *(const int4*)&s0v[j + 6];
        int4 q0 = *(const int4*)&s1v[j];
        int4 q1 = *(const int4*)&s1v[j + 2];
        int4 q2 = *(const int4*)&s1v[j + 4];
        int4 q3 = *(const int4*)&s1v[j + 6];
        float f0v = h_at(wcat, (uint_t)p0.x + t2);
        float f1v = h_at(wcat, (uint_t)p0.z + t2);
        float f2v = h_at(wcat, (uint_t)p1.x + t2);
        float f3v = h_at(wcat, (uint_t)p1.z + t2);
        float f4v = h_at(wcat, (uint_t)p2.x + t2);
        float f5v = h_at(wcat, (uint_t)p2.z + t2);
        float f6v = h_at(wcat, (uint_t)p3.x + t2);
        float f7v = h_at(wcat, (uint_t)p3.z + t2);
        float g0v = h_at(wcat, (uint_t)q0.x + t2);
        float g1v = h_at(wcat, (uint_t)q0.z + t2);
        float g2v = h_at(wcat, (uint_t)q1.x + t2);
        float g3v = h_at(wcat, (uint_t)q1.z + t2);
        float g4v = h_at(wcat, (uint_t)q2.x + t2);
        float g5v = h_at(wcat, (uint_t)q2.z + t2);
        float g6v = h_at(wcat, (uint_t)q3.x + t2);
        float g7v = h_at(wcat, (uint_t)q3.z + t2);
        acc0 = fmaf(__int_as_float(p0.y), f0v, acc0);
        acc0 = fmaf(__int_as_float(p0.w), f1v, acc0);
        acc0 = fmaf(__int_as_float(p1.y), f2v, acc0);
        acc0 = fmaf(__int_as_float(p1.w), f3v, acc0);
        acc0 = fmaf(__int_as_float(p2.y), f4v, acc0);
        acc0 = fmaf(__int_as_float(p2.w), f5v, acc0);
        acc0 = fmaf(__int_as_float(p3.y), f6v, acc0);
        acc0 = fmaf(__int_as_float(p3.w), f7v, acc0);
        acc1 = fmaf(__int_as_float(q0.y), g0v, acc1);
        acc1 = fmaf(__int_as_float(q0.w), g1v, acc1);
        acc1 = fmaf(__int_as_float(q1.y), g2v, acc1);
        acc1 = fmaf(__int_as_float(q1.w), g3v, acc1);
        acc1 = fmaf(__int_as_float(q2.y), g4v, acc1);
        acc1 = fmaf(__int_as_float(q2.w), g5v, acc1);
        acc1 = fmaf(__int_as_float(q3.y), g6v, acc1);
        acc1 = fmaf(__int_as_float(q3.w), g7v, acc1);
    }
    acc0 = fmaxf(acc0, 0.0f);
    acc1 = fmaxf(acc1, 0.0f);
    if (br == 0) {
        hb[(size_t)r0 * 192 + c] = (_Float16)acc0;
        hb[(size_t)r1 * 192 + c] = (_Float16)acc1;
    } else {
        xb[(size_t)r0 * 128 + (size_t)(br - 1) * 64 + c] = (_Float16)acc0;
        xb[(size_t)r1 * 128 + (size_t)(br - 1) * 64 + c] = (_Float16)acc1;
    }
}

// hop1: y = A @ xb. Slab e.x = col*128; xb byte stride 256 -> off = (e.x<<1)+t2.
// One block (2 waves) per ROW PAIR. branch1 -> hb[:,64:128]; branch2 -> tmp.
__global__ void hop1_kernel(const int* __restrict__ fill, const int2* __restrict__ slab,
                            const _Float16* __restrict__ xb,
                            _Float16* __restrict__ hb, _Float16* __restrict__ tmp) {
    int bp = blockIdx.x;
    int r0 = 2 * bp, r1 = 2 * bp + 1;
    int t = threadIdx.x;        // 0..127
    float acc0 = 0.0f, acc1 = 0.0f;
    uint_t t2 = 2u * (uint_t)t;
    const int2* s0v = slab + (size_t)r0 * SLAB_A;
    const int2* s1v = slab + (size_t)r1 * SLAB_A;
    int f0 = min(fill[r0], SLAB_A);
    int f1 = min(fill[r1], SLAB_A);
    int e  = (max(f0, f1) + 7) & ~7;
    for (int j = 0; j < e; j += 8) {
        int4 p0 = *(const int4*)&s0v[j];
        int4 p1 = *(const int4*)&s0v[j + 2];
        int4 p2 = *(const int4*)&s0v[j + 4];
        int4 p3 = *(const int4*)&s0v[j + 6];
        int4 q0 = *(const int4*)&s1v[j];
        int4 q1 = *(const int4*)&s1v[j + 2];
        int4 q2 = *(const int4*)&s1v[j + 4];
        int4 q3 = *(const int4*)&s1v[j + 6];
        float f0v = h_at(xb, ((uint_t)p0.x << 1) + t2);
        float f1v = h_at(xb, ((uint_t)p0.z << 1) + t2);
        float f2v = h_at(xb, ((uint_t)p1.x << 1) + t2);
        float f3v = h_at(xb, ((uint_t)p1.z << 1) + t2);
        float f4v = h_at(xb, ((uint_t)p2.x << 1) + t2);
        float f5v = h_at(xb, ((uint_t)p2.z << 1) + t2);
        float f6v = h_at(xb, ((uint_t)p3.x << 1) + t2);
        float f7v = h_at(xb, ((uint_t)p3.z << 1) + t2);
        float g0v = h_at(xb, ((uint_t)q0.x << 1) + t2);
        float g1v = h_at(xb, ((uint_t)q0.z << 1) + t2);
        float g2v = h_at(xb, ((uint_t)q1.x << 1) + t2);
        float g3v = h_at(xb, ((uint_t)q1.z << 1) + t2);
        float g4v = h_at(xb, ((uint_t)q2.x << 1) + t2);
        float g5v = h_at(xb, ((uint_t)q2.z << 1) + t2);
        float g6v = h_at(xb, ((uint_t)q3.x << 1) + t2);
        float g7v = h_at(xb, ((uint_t)q3.z << 1) + t2);
        acc0 = fmaf(__int_as_float(p0.y), f0v, acc0);
        acc0 = fmaf(__int_as_float(p0.w), f1v, acc0);
        acc0 = fmaf(__int_as_float(p1.y), f2v, acc0);
        acc0 = fmaf(__int_as_float(p1.w), f3v, acc0);
        acc0 = fmaf(__int_as_float(p2.y), f4v, acc0);
        acc0 = fmaf(__int_as_float(p2.w), f5v, acc0);
        acc0 = fmaf(__int_as_float(p3.y), f6v, acc0);
        acc0 = fmaf(__int_as_float(p3.w), f7v, acc0);
        acc1 = fmaf(__int_as_float(q0.y), g0v, acc1);
        acc1 = fmaf(__int_as_float(q0.w), g1v, acc1);
        acc1 = fmaf(__int_as_float(q1.y), g2v, acc1);
        acc1 = fmaf(__int_as_float(q1.w), g3v, acc1);
        acc1 = fmaf(__int_as_float(q2.y), g4v, acc1);
        acc1 = fmaf(__int_as_float(q2.w), g5v, acc1);
        acc1 = fmaf(__int_as_float(q3.y), g6v, acc1);
        acc1 = fmaf(__int_as_float(q3.w), g7v, acc1);
    }
    if (t < 64) {
        hb[(size_t)r0 * 192 + 64 + t] = (_Float16)acc0;
        hb[(size_t)r1 * 192 + 64 + t] = (_Float16)acc1;
    } else {
        tmp[(size_t)r0 * 64 + (t - 64)] = (_Float16)acc0;
        tmp[(size_t)r1 * 64 + (t - 64)] = (_Float16)acc1;
    }
}

// hop2: branch2 second hop -> hb[:,128:192]. Slab e.x = col*128 = tmp byte off.
__global__ void hop2_kernel(const int* __restrict__ fill, const int2* __restrict__ slab,
                            const _Float16* __restrict__ tmp, _Float16* __restrict__ hb) {
    int bp = blockIdx.x;
    int r0 = 2 * bp, r1 = 2 * bp + 1;
    int t = threadIdx.x;        // 0..63
    float acc0 = 0.0f, acc1 = 0.0f;
    uint_t t2 = 2u * (uint_t)t;
    const int2* s0v = slab + (size_t)r0 * SLAB_A;
    const int2* s1v = slab + (size_t)r1 * SLAB_A;
    int f0 = min(fill[r0], SLAB_A);
    int f1 = min(fill[r1], SLAB_A);
    int e  = (max(f0, f1) + 7) & ~7;
    for (int j = 0; j < e; j += 8) {
        int4 p0 = *(const int4*)&s0v[j];
        int4 p1 = *(const int4*)&s0v[j + 2];
        int4 p2 = *(const int4*)&s0v[j + 4];
        int4 p3 = *(const int4*)&s0v[j + 6];
        int4 q0 = *(const int4*)&s1v[j];
        int4 q1 = *(const int4*)&s1v[j + 2];
        int4 q2 = *(const int4*)&s1v[j + 4];
        int4 q3 = *(const int4*)&s1v[j + 6];
        float f0v = h_at(tmp, (uint_t)p0.x + t2);
        float f1v = h_at(tmp, (uint_t)p0.z + t2);
        float f2v = h_at(tmp, (uint_t)p1.x + t2);
        float f3v = h_at(tmp, (uint_t)p1.z + t2);
        float f4v = h_at(tmp, (uint_t)p2.x + t2);
        float f5v = h_at(tmp, (uint_t)p2.z + t2);
        float f6v = h_at(tmp, (uint_t)p3.x + t2);
        float f7v = h_at(tmp, (uint_t)p3.z + t2);
        float g0v = h_at(tmp, (uint_t)q0.x + t2);
        float g1v = h_at(tmp, (uint_t)q0.z + t2);
        float g2v = h_at(tmp, (uint_t)q1.x + t2);
        float g3v = h_at(tmp, (uint_t)q1.z + t2);
        float g4v = h_at(tmp, (uint_t)q2.x + t2);
        float g5v = h_at(tmp, (uint_t)q2.z + t2);
        float g6v = h_at(tmp, (uint_t)q3.x + t2);
        float g7v = h_at(tmp, (uint_t)q3.z + t2);
        acc0 = fmaf(__int_as_float(p0.y), f0v, acc0);
        acc0 = fmaf(__int_as_float(p0.w), f1v, acc0);
        acc0 = fmaf(__int_as_float(p1.y), f2v, acc0);
        acc0 = fmaf(__int_as_float(p1.w), f3v, acc0);
        acc0 = fmaf(__int_as_float(p2.y), f4v, acc0);
        acc0 = fmaf(__int_as_float(p2.w), f5v, acc0);
        acc0 = fmaf(__int_as_float(p3.y), f6v, acc0);
        acc0 = fmaf(__int_as_float(p3.w), f7v, acc0);
        acc1 = fmaf(__int_as_float(q0.y), g0v, acc1);
        acc1 = fmaf(__int_as_float(q0.w), g1v, acc1);
        acc1 = fmaf(__int_as_float(q1.y), g2v, acc1);
        acc1 = fmaf(__int_as_float(q1.w), g3v, acc1);
        acc1 = fmaf(__int_as_float(q2.y), g4v, acc1);
        acc1 = fmaf(__int_as_float(q2.w), g5v, acc1);
        acc1 = fmaf(__int_as_float(q3.y), g6v, acc1);
        acc1 = fmaf(__int_as_float(q3.w), g7v, acc1);
    }
    hb[(size_t)r0 * 192 + 128 + t] = (_Float16)acc0;
    hb[(size_t)r1 * 192 + 128 + t] = (_Float16)acc1;
}

// ---------------------------------------------------------------------------
// FC + log_softmax via MFMA (f16). Block = 3 waves; wave nt owns 16 cols;
// 16 rows per block; K=192 = 6 x mfma_f32_16x16x32_f16.
// ---------------------------------------------------------------------------
__global__ void fc_mfma_kernel(const _Float16* __restrict__ hb,
                               const _Float16* __restrict__ fcwB,
                               const float* __restrict__ fc_b,
                               float* __restrict__ out) {
    int wave = threadIdx.x >> 6;      // 0..2 = N-tile
    int lane = threadIdx.x & 63;
    int m16  = lane & 15;
    int quad = lane >> 4;
    size_t rowbase = (size_t)blockIdx.x * 16;

    float4v acc = {0.f, 0.f, 0.f, 0.f};
    const _Float16* arow = hb   + (rowbase + m16) * 192 + quad * 8;
    const _Float16* brow = fcwB + (size_t)(wave * 16 + m16) * 192 + quad * 8;
#pragma unroll
    for (int s = 0; s < 6; ++s) {
        half8v a = *(const half8v*)(arow + s * 32);
        half8v b = *(const half8v*)(brow + s * 32);
        acc = __builtin_amdgcn_mfma_f32_16x16x32_f16(a, b, acc, 0, 0, 0);
    }

    __shared__ float lds[16][49];     // 48 cols + pad
    __shared__ float s_lse[16];
    int col = wave * 16 + m16;
    float bias = (col < NCLS) ? fc_b[col] : 0.0f;
#pragma unroll
    for (int i = 0; i < 4; ++i) {
        lds[quad * 4 + i][col] = acc[i] + bias;
    }
    __syncthreads();
    if (threadIdx.x < 16) {
        int row = threadIdx.x;
        float m = -INFINITY;
        for (int c = 0; c < NCLS; ++c) m = fmaxf(m, lds[row][c]);
        float s = 0.0f;
        for (int c = 0; c < NCLS; ++c) s += expf(lds[row][c] - m);
        s_lse[row] = m + logf(s);
    }
    __syncthreads();
    for (int idx = threadIdx.x; idx < 16 * NCLS; idx += 192) {
        int row = idx / NCLS, c = idx - row * NCLS;
        out[(rowbase + row) * NCLS + c] = lds[row][c] - s_lse[row];
    }
}

// ---------------------------------------------------------------------------

extern "C" void kernel_launch(void* const* d_in, const int* in_sizes, int n_in,
                              void* d_out, int out_size, void* d_ws, size_t ws_size,
                              hipStream_t stream) {
    const int*   adj_idx  = (const int*)  d_in[0];
    const float* adj_val  = (const float*)d_in[1];
    const int*   feat_idx = (const int*)  d_in[2];
    const float* feat_val = (const float*)d_in[3];
    const float* w1 = (const float*)d_in[4];
    const float* b1 = (const float*)d_in[5];
    const float* w2 = (const float*)d_in[6];
    const float* b2 = (const float*)d_in[7];
    const float* w3 = (const float*)d_in[8];
    const float* b3 = (const float*)d_in[9];
    const float* fc_w = (const float*)d_in[10];
    const float* fc_b = (const float*)d_in[11];
    float* out = (float*)d_out;

    char* ws = (char*)d_ws;
    size_t off = 0;
    auto take = [&](size_t bytes) -> char* {
        char* p = ws + off;
        off = (off + bytes + 255) & ~(size_t)255;
        return p;
    };
    // Dense fills (FILL_STRIDE retired: no global atomics touch fills anymore;
    // bscatter plain-stores every row, so no memset of fills needed either).
    int*  featFill = (int*)take((size_t)N_NODES * sizeof(int));                   // 200 KB
    int*  adjFill  = (int*)take((size_t)N_NODES * sizeof(int));                   // 200 KB
    int*  bfF      = (int*)take(2048 * sizeof(int));                              // 8 KB (memset)
    int*  bfA      = bfF + 1024;
    int2* featSlab = (int2*)take((size_t)N_NODES * SLAB_F * sizeof(int2));        // 32 MB
    int2* adjSlab  = (int2*)take((size_t)N_NODES * SLAB_A * sizeof(int2));        // 19.2 MB
    _Float16* wcat = (_Float16*)take((size_t)F_IN * 192 * sizeof(_Float16));      // 0.79 MB
    _Float16* fcwB = (_Float16*)take((size_t)48 * 192 * sizeof(_Float16));        // 18 KB
    _Float16* xb   = (_Float16*)take((size_t)N_NODES * 128 * sizeof(_Float16));   // 12.8 MB
    _Float16* hb   = (_Float16*)take((size_t)N_NODES * 192 * sizeof(_Float16));   // 19.2 MB
    // Aliases (no new workspace):
    //   barrF (14.2 MB) -> hb (19.2 MB): dead once bscatter completes.
    //   barrA ( 7.5 MB) -> xb (12.8 MB): dead once bscatter completes.
    //   tmp   ( 6.4 MB) -> featSlab (32 MB): featSlab dead after spmm_feat.
    int2* barrF = (int2*)hb;
    int2* barrA = (int2*)xb;
    _Float16* tmp = (_Float16*)featSlab;

    hipMemsetAsync(bfF, 0, 2048 * sizeof(int), stream);

    partition_prep_kernel<<<FEAT_CHUNKS + ADJ_CHUNKS + PREP_BLOCKS, 256, 0, stream>>>(
        feat_idx, feat_val, adj_idx, adj_val, bfF, barrF, bfA, barrA,
        w1, w2, w3, wcat, fc_w, fcwB);

    bscatter_kernel<<<2 * NBUCK, 256, 0, stream>>>(
        bfF, barrF, bfA, barrA, featFill, featSlab, adjFill, adjSlab);

    spmm_feat_kernel<<<N_NODES / 2, 192, 0, stream>>>(featFill, featSlab, wcat,
                                                      b1, b2, b3, hb, xb);
    hop1_kernel<<<N_NODES / 2, 128, 0, stream>>>(adjFill, adjSlab, xb, hb, tmp);
    hop2_kernel<<<N_NODES / 2, 64, 0, stream>>>(adjFill, adjSlab, tmp, hb);
    fc_mfma_kernel<<<N_NODES / 16, 192, 0, stream>>>(hb, fcwB, fc_b, out);
}